// Round 3
// baseline (424.862 us; speedup 1.0000x reference)
//
#include <hip/hip_runtime.h>
#include <stdint.h>
#include <stddef.h>

#define B_ 2
#define S_ 2048
#define D_ 1024
#define H_ 16
#define HD_ 64
#define FF_ 4096

typedef unsigned short u16;
typedef __attribute__((ext_vector_type(8))) short bf16x8;
typedef __attribute__((ext_vector_type(4))) float f32x4;

__device__ __forceinline__ u16 f2bf(float f) {
  unsigned u = __float_as_uint(f);
  u += 0x7fffu + ((u >> 16) & 1u);
  return (u16)(u >> 16);
}

__device__ __forceinline__ f32x4 mfma16(bf16x8 a, bf16x8 b, f32x4 c) {
  return __builtin_amdgcn_mfma_f32_16x16x32_bf16(a, b, c, 0, 0, 0);
}

__device__ __forceinline__ void gload16(const void* g, void* l) {
  __builtin_amdgcn_global_load_lds(
      (const __attribute__((address_space(1))) void*)g,
      (__attribute__((address_space(3))) void*)l, 16, 0, 0);
}

// XCD-aware block swizzle (bijective when gridDim.x % 8 == 0).
__device__ __forceinline__ void swizzle_mn(int& mt, int& nt) {
  int gm = gridDim.x;
  if ((gm & 7) == 0) {
    int bid = blockIdx.y * gm + blockIdx.x;
    int mper = gm >> 3;
    int xcd = bid & 7, idx = bid >> 3;
    mt = xcd * mper + (idx % mper);
    nt = idx / mper;
  } else {
    mt = blockIdx.x;
    nt = blockIdx.y;
  }
}

// ---------------- fused prep: x cvt + all weight transposes ----------------
// linear grid, bid-decoded:
//   [0,4096)      W1 transpose tiles (K=1024 x N=4096)
//   [4096,8192)   W2 transpose tiles (K=4096 x N=1024)
//   [8192,12288)  x fp32->bf16 (4096 blocks x 1024 elems)
//   [12288,16384) 4 x DxD transposes (Wq,Wk,Wv,Wo)
__global__ __launch_bounds__(256) void prep_kernel(
    const float* __restrict__ x, u16* __restrict__ xb,
    const float* __restrict__ W1, u16* __restrict__ w1T,
    const float* __restrict__ W2, u16* __restrict__ w2T,
    const float* __restrict__ Wq, const float* __restrict__ Wk,
    const float* __restrict__ Wv, const float* __restrict__ Wo,
    u16* __restrict__ wTq, u16* __restrict__ wTk,
    u16* __restrict__ wTv, u16* __restrict__ wTo) {
  int bid = blockIdx.x;
  int tid = threadIdx.x;
  if (bid >= 8192 && bid < 12288) {  // cvt path (no barrier)
    int i = (bid - 8192) * 1024 + tid * 4;
    float4 v = *(const float4*)(x + i);
    ushort4 o = { f2bf(v.x), f2bf(v.y), f2bf(v.z), f2bf(v.w) };
    *(ushort4*)(xb + i) = o;
    return;
  }
  const float* W;
  u16* WT;
  int K, N, k0, n0;
  if (bid < 4096) {  // W1
    W = W1; WT = w1T; K = 1024; N = 4096;
    k0 = (bid & 31) * 32; n0 = (bid >> 5) * 32;
  } else if (bid < 8192) {  // W2
    int b2 = bid - 4096;
    W = W2; WT = w2T; K = 4096; N = 1024;
    k0 = (b2 >> 5) * 32; n0 = (b2 & 31) * 32;
  } else {  // 4 x DxD
    int t = bid - 12288;
    int z = t >> 10, r = t & 1023;
    W = z == 0 ? Wq : (z == 1 ? Wk : (z == 2 ? Wv : Wo));
    WT = z == 0 ? wTq : (z == 1 ? wTk : (z == 2 ? wTv : wTo));
    K = 1024; N = 1024;
    k0 = (r & 31) * 32; n0 = (r >> 5) * 32;
  }
  __shared__ u16 t[32][33];
  int r = tid >> 3;
  int c = (tid & 7) << 2;
  float4 v = *(const float4*)(W + (size_t)(k0 + r) * N + n0 + c);
  t[r][c + 0] = f2bf(v.x); t[r][c + 1] = f2bf(v.y);
  t[r][c + 2] = f2bf(v.z); t[r][c + 3] = f2bf(v.w);
  __syncthreads();
  ushort4 o;
  o.x = t[c + 0][r]; o.y = t[c + 1][r]; o.z = t[c + 2][r]; o.w = t[c + 3][r];
  *(ushort4*)(WT + (size_t)(n0 + r) * K + k0 + c) = o;
}

// ---------------- GEMM 128x128, out bf16 + relu (+bias)  [ffn1] ------------
// launch_bounds(256,4): VGPR<=128 -> 4 blocks/CU -> 1024-block grid = 1 round
__global__ __launch_bounds__(256, 4) void gemm_bt_relu(
    const u16* __restrict__ A, const u16* __restrict__ BT,
    const float* __restrict__ bias, u16* __restrict__ outp,
    int M, int N, int K) {
  __shared__ __align__(16) u16 As[128 * 32];
  __shared__ __align__(16) u16 Bs[128 * 32];
  int tid = threadIdx.x;
  int lane = tid & 63;
  int wave = tid >> 6;
  int quad = lane >> 4;
  int l16 = lane & 15;
  int mt, nt;
  swizzle_mn(mt, nt);
  int m0 = mt * 128;
  int n0 = nt * 128;
  int wm = (wave >> 1) * 64;
  int wn = (wave & 1) * 64;

  f32x4 zero = {0.f, 0.f, 0.f, 0.f};
  f32x4 acc[4][4];
#pragma unroll
  for (int i = 0; i < 4; i++)
#pragma unroll
    for (int j = 0; j < 4; j++) acc[i][j] = zero;

  int c0 = tid, c1 = tid + 256;
  const u16* ga0 = A + (size_t)(m0 + (c0 >> 2)) * K + (c0 & 3) * 8;
  const u16* ga1 = A + (size_t)(m0 + (c1 >> 2)) * K + (c1 & 3) * 8;
  const u16* gb0 = BT + (size_t)(n0 + (c0 >> 2)) * K + (c0 & 3) * 8;
  const u16* gb1 = BT + (size_t)(n0 + (c1 >> 2)) * K + (c1 & 3) * 8;

  for (int k0 = 0; k0 < K; k0 += 32) {
    gload16(ga0 + k0, &As[c0 * 8]);
    gload16(ga1 + k0, &As[c1 * 8]);
    gload16(gb0 + k0, &Bs[c0 * 8]);
    gload16(gb1 + k0, &Bs[c1 * 8]);
    __syncthreads();
    bf16x8 af[4], bfr[4];
#pragma unroll
    for (int i = 0; i < 4; i++)
      af[i] = *(const bf16x8*)&As[(wm + i * 16 + l16) * 32 + quad * 8];
#pragma unroll
    for (int j = 0; j < 4; j++)
      bfr[j] = *(const bf16x8*)&Bs[(wn + j * 16 + l16) * 32 + quad * 8];
#pragma unroll
    for (int i = 0; i < 4; i++)
#pragma unroll
      for (int j = 0; j < 4; j++)
        acc[i][j] = mfma16(af[i], bfr[j], acc[i][j]);
    __syncthreads();
  }

#pragma unroll
  for (int j = 0; j < 4; j++) {
    int gcol = n0 + wn + j * 16 + l16;
    float bv = bias[gcol];
#pragma unroll
    for (int i = 0; i < 4; i++) {
#pragma unroll
      for (int r = 0; r < 4; r++) {
        int grow = m0 + wm + i * 16 + quad * 4 + r;
        float val = acc[i][j][r] + bv;
        outp[(size_t)grow * N + gcol] = f2bf(val > 0.f ? val : 0.f);
      }
    }
  }
}

// ---------------- GEMM 128x128 split-K (up to 4), separate fp32 outputs ----
__global__ __launch_bounds__(256, 4) void gemm_bt_sk4(
    const u16* __restrict__ A, const u16* __restrict__ BT,
    const float* __restrict__ bias,
    float* __restrict__ o0, float* __restrict__ o1,
    float* __restrict__ o2, float* __restrict__ o3,
    int M, int N, int K, int Kc) {
  __shared__ __align__(16) u16 As[128 * 32];
  __shared__ __align__(16) u16 Bs[128 * 32];
  int tid = threadIdx.x;
  int lane = tid & 63;
  int wave = tid >> 6;
  int quad = lane >> 4;
  int l16 = lane & 15;
  int mt, nt;
  swizzle_mn(mt, nt);
  int m0 = mt * 128;
  int n0 = nt * 128;
  int z = blockIdx.z;
  int kb = z * Kc;
  int wm = (wave >> 1) * 64;
  int wn = (wave & 1) * 64;

  f32x4 zero = {0.f, 0.f, 0.f, 0.f};
  f32x4 acc[4][4];
#pragma unroll
  for (int i = 0; i < 4; i++)
#pragma unroll
    for (int j = 0; j < 4; j++) acc[i][j] = zero;

  int c0 = tid, c1 = tid + 256;
  const u16* ga0 = A + (size_t)(m0 + (c0 >> 2)) * K + (c0 & 3) * 8 + kb;
  const u16* ga1 = A + (size_t)(m0 + (c1 >> 2)) * K + (c1 & 3) * 8 + kb;
  const u16* gb0 = BT + (size_t)(n0 + (c0 >> 2)) * K + (c0 & 3) * 8 + kb;
  const u16* gb1 = BT + (size_t)(n0 + (c1 >> 2)) * K + (c1 & 3) * 8 + kb;

  for (int k0 = 0; k0 < Kc; k0 += 32) {
    gload16(ga0 + k0, &As[c0 * 8]);
    gload16(ga1 + k0, &As[c1 * 8]);
    gload16(gb0 + k0, &Bs[c0 * 8]);
    gload16(gb1 + k0, &Bs[c1 * 8]);
    __syncthreads();
    bf16x8 af[4], bfr[4];
#pragma unroll
    for (int i = 0; i < 4; i++)
      af[i] = *(const bf16x8*)&As[(wm + i * 16 + l16) * 32 + quad * 8];
#pragma unroll
    for (int j = 0; j < 4; j++)
      bfr[j] = *(const bf16x8*)&Bs[(wn + j * 16 + l16) * 32 + quad * 8];
#pragma unroll
    for (int i = 0; i < 4; i++)
#pragma unroll
      for (int j = 0; j < 4; j++)
        acc[i][j] = mfma16(af[i], bfr[j], acc[i][j]);
    __syncthreads();
  }

  float* outz = z == 0 ? o0 : (z == 1 ? o1 : (z == 2 ? o2 : o3));
  float biasmul = (z == 0) ? 1.f : 0.f;
#pragma unroll
  for (int j = 0; j < 4; j++) {
    int gcol = n0 + wn + j * 16 + l16;
    float bv = bias[gcol] * biasmul;
#pragma unroll
    for (int i = 0; i < 4; i++) {
#pragma unroll
      for (int r = 0; r < 4; r++) {
        int grow = m0 + wm + i * 16 + quad * 4 + r;
        outz[(size_t)grow * N + gcol] = acc[i][j][r] + bv;
      }
    }
  }
}

// ---------------- fused QKV GEMM (q pre-scaled by 1/sqrt(HD)*log2e) --------
__global__ __launch_bounds__(256) void gemm_qkv(
    const u16* __restrict__ A, const u16* __restrict__ BT,
    const float* __restrict__ bq, const float* __restrict__ bk,
    const float* __restrict__ bvp,
    u16* __restrict__ qb, u16* __restrict__ kb, u16* __restrict__ vb) {
  const int K = 1024;
  __shared__ __align__(16) u16 As[128 * 32];
  __shared__ __align__(16) u16 Bs[128 * 32];
  int tid = threadIdx.x;
  int lane = tid & 63;
  int wave = tid >> 6;
  int quad = lane >> 4;
  int l16 = lane & 15;
  int mt, nt;
  swizzle_mn(mt, nt);
  int m0 = mt * 128;
  int n0 = nt * 128;
  int wm = (wave >> 1) * 64;
  int wn = (wave & 1) * 64;

  f32x4 zero = {0.f, 0.f, 0.f, 0.f};
  f32x4 acc[4][4];
#pragma unroll
  for (int i = 0; i < 4; i++)
#pragma unroll
    for (int j = 0; j < 4; j++) acc[i][j] = zero;

  int c0 = tid, c1 = tid + 256;
  const u16* ga0 = A + (size_t)(m0 + (c0 >> 2)) * K + (c0 & 3) * 8;
  const u16* ga1 = A + (size_t)(m0 + (c1 >> 2)) * K + (c1 & 3) * 8;
  const u16* gb0 = BT + (size_t)(n0 + (c0 >> 2)) * K + (c0 & 3) * 8;
  const u16* gb1 = BT + (size_t)(n0 + (c1 >> 2)) * K + (c1 & 3) * 8;

  for (int k0 = 0; k0 < K; k0 += 32) {
    gload16(ga0 + k0, &As[c0 * 8]);
    gload16(ga1 + k0, &As[c1 * 8]);
    gload16(gb0 + k0, &Bs[c0 * 8]);
    gload16(gb1 + k0, &Bs[c1 * 8]);
    __syncthreads();
    bf16x8 af[4], bfr[4];
#pragma unroll
    for (int i = 0; i < 4; i++)
      af[i] = *(const bf16x8*)&As[(wm + i * 16 + l16) * 32 + quad * 8];
#pragma unroll
    for (int j = 0; j < 4; j++)
      bfr[j] = *(const bf16x8*)&Bs[(wn + j * 16 + l16) * 32 + quad * 8];
#pragma unroll
    for (int i = 0; i < 4; i++)
#pragma unroll
      for (int j = 0; j < 4; j++)
        acc[i][j] = mfma16(af[i], bfr[j], acc[i][j]);
    __syncthreads();
  }

  int region = n0 >> 10;
  const float* bias = region == 0 ? bq : (region == 1 ? bk : bvp);
  u16* outp = region == 0 ? qb : (region == 1 ? kb : vb);
  float scale = region == 0 ? 0.125f * 1.4426950408889634f : 1.f;

#pragma unroll
  for (int j = 0; j < 4; j++) {
    int gcol = (n0 & 1023) + wn + j * 16 + l16;
    float bv = bias[gcol];
    int h = gcol >> 6, hd = gcol & 63;
#pragma unroll
    for (int i = 0; i < 4; i++) {
#pragma unroll
      for (int r = 0; r < 4; r++) {
        int grow = m0 + wm + i * 16 + quad * 4 + r;
        float val = (acc[i][j][r] + bv) * scale;
        int b = grow >> 11, s = grow & 2047;
        if (region < 2) {
          outp[(((size_t)(b * H_ + h)) * S_ + s) * HD_ + hd] = f2bf(val);
        } else {
          outp[(((size_t)(b * H_ + h)) * HD_ + hd) * S_ + s] = f2bf(val);
        }
      }
    }
  }
}

// ---------------- flash attention: MQ=32/wave, K/V direct from L2 ----------
// Head-grouped XCD swizzle keeps each head's K+V (512 KB) in its XCD's L2
// (4 heads x 512 KB = 2 MB < 4 MB). No K/V LDS staging, no barriers; only
// LDS is the per-wave-private P buffer (18432 B). 16 independent b128
// global loads in flight per K-tile iteration.
__global__ __launch_bounds__(256, 2) void attn_kernel(
    const u16* __restrict__ q, const u16* __restrict__ k,
    const u16* __restrict__ vt, const int* __restrict__ mask,
    u16* __restrict__ ao) {
  __shared__ __align__(16) u16 Ps[4][32 * 72];
  int tid = threadIdx.x;
  int lane = tid & 63;
  int wave = tid >> 6;
  int quad = lane >> 4;
  int l16 = lane & 15;

  // head-grouped decode: lin%8 -> XCD (validated: FETCH 71.8->12.4 MB)
  int lin = blockIdx.y * gridDim.x + blockIdx.x;  // 0..511
  int xcd = lin & 7;
  int t = lin >> 3;        // 0..63
  int qt = t & 15;         // q-tile (128 rows)
  int hh = t >> 4;         // 0..3
  int bh = hh * 8 + xcd;
  int b = bh >> 4;
  int h = bh & 15;
  int qrow0 = qt * 128 + wave * 32;

  const u16* qh = q + (size_t)bh * S_ * HD_;
  const u16* kh = k + (size_t)bh * S_ * HD_;
  const u16* vh = vt + (size_t)bh * HD_ * S_;

  bf16x8 qfA0 = *(const bf16x8*)(qh + (size_t)(qrow0 + l16) * HD_ + quad * 8);
  bf16x8 qfA1 = *(const bf16x8*)(qh + (size_t)(qrow0 + l16) * HD_ + 32 + quad * 8);
  bf16x8 qfB0 = *(const bf16x8*)(qh + (size_t)(qrow0 + 16 + l16) * HD_ + quad * 8);
  bf16x8 qfB1 = *(const bf16x8*)(qh + (size_t)(qrow0 + 16 + l16) * HD_ + 32 + quad * 8);

  // K fragment base pointers: even rows (2*l16) / odd rows (2*l16+1)
  const u16* ke = kh + (size_t)(2 * l16) * HD_ + quad * 8;
  const u16* kod = kh + (size_t)(2 * l16 + 1) * HD_ + quad * 8;
  // V^T fragment base: row l16 (+c*16), col kt + quad*8
  const u16* vbase = vh + (size_t)l16 * S_ + quad * 8;
  const int* mrow = mask + b * S_ + 2 * l16;

  float l_pA[4] = {0.f, 0.f, 0.f, 0.f};
  float l_pB[4] = {0.f, 0.f, 0.f, 0.f};
  f32x4 zero = {0.f, 0.f, 0.f, 0.f};
  f32x4 o_accA[4], o_accB[4];
#pragma unroll
  for (int c = 0; c < 4; c++) { o_accA[c] = zero; o_accB[c] = zero; }

  u16* pw = &Ps[wave][0];

  for (int kt = 0; kt < S_; kt += 64) {
    int2 mk0 = *(const int2*)(mrow + kt);
    int2 mk1 = *(const int2*)(mrow + kt + 32);

    // issue all 16 fragment loads up front (independent -> deep MLP)
    const u16* ke0p = ke + (size_t)kt * HD_;
    const u16* ko0p = kod + (size_t)kt * HD_;
    const u16* ke1p = ke + (size_t)(kt + 32) * HD_;
    const u16* ko1p = kod + (size_t)(kt + 32) * HD_;
    bf16x8 e00 = *(const bf16x8*)(ke0p);
    bf16x8 e01 = *(const bf16x8*)(ke0p + 32);
    bf16x8 o00 = *(const bf16x8*)(ko0p);
    bf16x8 o01 = *(const bf16x8*)(ko0p + 32);
    bf16x8 e10 = *(const bf16x8*)(ke1p);
    bf16x8 e11 = *(const bf16x8*)(ke1p + 32);
    bf16x8 o10 = *(const bf16x8*)(ko1p);
    bf16x8 o11 = *(const bf16x8*)(ko1p + 32);
    bf16x8 vf[4][2];
#pragma unroll
    for (int c = 0; c < 4; c++) {
      const u16* vp = vbase + (size_t)(c * 16) * S_ + kt;
      vf[c][0] = *(const bf16x8*)(vp);
      vf[c][1] = *(const bf16x8*)(vp + 32);
    }

#pragma unroll
    for (int g = 0; g < 2; g++) {
      int2 mk = g == 0 ? mk0 : mk1;
      bf16x8 e0 = g == 0 ? e00 : e10;
      bf16x8 e1 = g == 0 ? e01 : e11;
      bf16x8 o0 = g == 0 ? o00 : o10;
      bf16x8 o1 = g == 0 ? o01 : o11;
      f32x4 seA = mfma16(qfA1, e1, mfma16(qfA0, e0, zero));
      f32x4 soA = mfma16(qfA1, o1, mfma16(qfA0, o0, zero));
      f32x4 seB = mfma16(qfB1, e1, mfma16(qfB0, e0, zero));
      f32x4 soB = mfma16(qfB1, o1, mfma16(qfB0, o0, zero));
#pragma unroll
      for (int r = 0; r < 4; r++) {
        float pA0 = mk.x ? exp2f(seA[r]) : 0.f;
        float pA1 = mk.y ? exp2f(soA[r]) : 0.f;
        float pB0 = mk.x ? exp2f(seB[r]) : 0.f;
        float pB1 = mk.y ? exp2f(soB[r]) : 0.f;
        l_pA[r] += pA0 + pA1;
        l_pB[r] += pB0 + pB1;
        unsigned pkA = __builtin_amdgcn_perm(__float_as_uint(pA1),
                                             __float_as_uint(pA0), 0x07060302u);
        unsigned pkB = __builtin_amdgcn_perm(__float_as_uint(pB1),
                                             __float_as_uint(pB0), 0x07060302u);
        *(unsigned*)&pw[(quad * 4 + r) * 72 + g * 32 + 2 * l16] = pkA;
        *(unsigned*)&pw[(16 + quad * 4 + r) * 72 + g * 32 + 2 * l16] = pkB;
      }
    }
    bf16x8 pfA0 = *(const bf16x8*)&pw[l16 * 72 + quad * 8];
    bf16x8 pfA1 = *(const bf16x8*)&pw[l16 * 72 + 32 + quad * 8];
    bf16x8 pfB0 = *(const bf16x8*)&pw[(16 + l16) * 72 + quad * 8];
    bf16x8 pfB1 = *(const bf16x8*)&pw[(16 + l16) * 72 + 32 + quad * 8];
#pragma unroll
    for (int c = 0; c < 4; c++) {
      o_accA[c] = mfma16(pfA1, vf[c][1], mfma16(pfA0, vf[c][0], o_accA[c]));
      o_accB[c] = mfma16(pfB1, vf[c][1], mfma16(pfB0, vf[c][0], o_accB[c]));
    }
  }

#pragma unroll
  for (int r = 0; r < 4; r++) {
    float sA = l_pA[r], sB = l_pB[r];
#pragma unroll
    for (int off = 1; off < 16; off <<= 1) {
      sA += __shfl_xor(sA, off);
      sB += __shfl_xor(sB, off);
    }
    float invA = 1.f / sA, invB = 1.f / sB;
    int srowA = qrow0 + quad * 4 + r;
    int srowB = qrow0 + 16 + quad * 4 + r;
#pragma unroll
    for (int c = 0; c < 4; c++) {
      ao[((size_t)(b * S_ + srowA)) * D_ + h * HD_ + c * 16 + l16] =
          f2bf(o_accA[c][r] * invA);
      ao[((size_t)(b * S_ + srowB)) * D_ + h * HD_ + c * 16 + l16] =
          f2bf(o_accB[c][r] * invB);
    }
  }
}

// ---------------- residual (2 partials) + layernorm ----------------
__global__ __launch_bounds__(256) void ln_kernel(
    const float* __restrict__ xa, const float* __restrict__ add0,
    const float* __restrict__ add1,
    const float* __restrict__ g, const float* __restrict__ be,
    float* __restrict__ outf, u16* __restrict__ outb) {
  int row = blockIdx.x;
  int tid = threadIdx.x;
  int lane = tid & 63;
  int wv = tid >> 6;
  const float4 a = *(const float4*)(xa + (size_t)row * D_ + tid * 4);
  const float4 c = *(const float4*)(add0 + (size_t)row * D_ + tid * 4);
  const float4 d = *(const float4*)(add1 + (size_t)row * D_ + tid * 4);
  float v0 = a.x + c.x + d.x, v1 = a.y + c.y + d.y;
  float v2 = a.z + c.z + d.z, v3 = a.w + c.w + d.w;
  float s = v0 + v1 + v2 + v3;
  float sq = v0 * v0 + v1 * v1 + v2 * v2 + v3 * v3;
#pragma unroll
  for (int off = 1; off < 64; off <<= 1) {
    s += __shfl_xor(s, off);
    sq += __shfl_xor(sq, off);
  }
  __shared__ float red[8];
  if (lane == 0) { red[wv] = s; red[4 + wv] = sq; }
  __syncthreads();
  s = red[0] + red[1] + red[2] + red[3];
  sq = red[4] + red[5] + red[6] + red[7];
  float mean = s * (1.f / D_);
  float var = sq * (1.f / D_) - mean * mean;
  float rstd = rsqrtf(var + 1e-5f);
  const float4 gv = *(const float4*)(g + tid * 4);
  const float4 bv = *(const float4*)(be + tid * 4);
  float y0 = (v0 - mean) * rstd * gv.x + bv.x;
  float y1 = (v1 - mean) * rstd * gv.y + bv.y;
  float y2 = (v2 - mean) * rstd * gv.z + bv.z;
  float y3 = (v3 - mean) * rstd * gv.w + bv.w;
  float4 o = {y0, y1, y2, y3};
  *(float4*)(outf + (size_t)row * D_ + tid * 4) = o;
  if (outb) {
    ushort4 ob = {f2bf(y0), f2bf(y1), f2bf(y2), f2bf(y3)};
    *(ushort4*)(outb + (size_t)row * D_ + tid * 4) = ob;
  }
}

// ---------------- residual (4 partials) + layernorm ----------------
__global__ __launch_bounds__(256) void ln4_kernel(
    const float* __restrict__ xa,
    const float* __restrict__ a0, const float* __restrict__ a1,
    const float* __restrict__ a2, const float* __restrict__ a3,
    const float* __restrict__ g, const float* __restrict__ be,
    float* __restrict__ outf, u16* __restrict__ outb) {
  int row = blockIdx.x;
  int tid = threadIdx.x;
  int lane = tid & 63;
  int wv = tid >> 6;
  size_t off0 = (size_t)row * D_ + tid * 4;
  const float4 a = *(const float4*)(xa + off0);
  const float4 c0 = *(const float4*)(a0 + off0);
  const float4 c1 = *(const float4*)(a1 + off0);
  const float4 c2 = *(const float4*)(a2 + off0);
  const float4 c3 = *(const float4*)(a3 + off0);
  float v0 = a.x + (c0.x + c1.x) + (c2.x + c3.x);
  float v1 = a.y + (c0.y + c1.y) + (c2.y + c3.y);
  float v2 = a.z + (c0.z + c1.z) + (c2.z + c3.z);
  float v3 = a.w + (c0.w + c1.w) + (c2.w + c3.w);
  float s = v0 + v1 + v2 + v3;
  float sq = v0 * v0 + v1 * v1 + v2 * v2 + v3 * v3;
#pragma unroll
  for (int off = 1; off < 64; off <<= 1) {
    s += __shfl_xor(s, off);
    sq += __shfl_xor(sq, off);
  }
  __shared__ float red[8];
  if (lane == 0) { red[wv] = s; red[4 + wv] = sq; }
  __syncthreads();
  s = red[0] + red[1] + red[2] + red[3];
  sq = red[4] + red[5] + red[6] + red[7];
  float mean = s * (1.f / D_);
  float var = sq * (1.f / D_) - mean * mean;
  float rstd = rsqrtf(var + 1e-5f);
  const float4 gv = *(const float4*)(g + tid * 4);
  const float4 bv = *(const float4*)(be + tid * 4);
  float y0 = (v0 - mean) * rstd * gv.x + bv.x;
  float y1 = (v1 - mean) * rstd * gv.y + bv.y;
  float y2 = (v2 - mean) * rstd * gv.z + bv.z;
  float y3 = (v3 - mean) * rstd * gv.w + bv.w;
  float4 o = {y0, y1, y2, y3};
  *(float4*)(outf + off0) = o;
  if (outb) {
    ushort4 ob = {f2bf(y0), f2bf(y1), f2bf(y2), f2bf(y3)};
    *(ushort4*)(outb + off0) = ob;
  }
}

extern "C" void kernel_launch(void* const* d_in, const int* in_sizes, int n_in,
                              void* d_out, int out_size, void* d_ws, size_t ws_size,
                              hipStream_t stream) {
  const float* x = (const float*)d_in[0];
  const int* mask = (const int*)d_in[1];
  const float* Wq = (const float*)d_in[2];
  const float* bq = (const float*)d_in[3];
  const float* Wk = (const float*)d_in[4];
  const float* bk = (const float*)d_in[5];
  const float* Wv = (const float*)d_in[6];
  const float* bv = (const float*)d_in[7];
  const float* Wo = (const float*)d_in[8];
  const float* bo = (const float*)d_in[9];
  const float* W1 = (const float*)d_in[10];
  const float* b1 = (const float*)d_in[11];
  const float* W2 = (const float*)d_in[12];
  const float* b2 = (const float*)d_in[13];
  const float* g1 = (const float*)d_in[14];
  const float* be1 = (const float*)d_in[15];
  const float* g2 = (const float*)d_in[16];
  const float* be2 = (const float*)d_in[17];

  const size_t MB = 1ull << 20;
  char* ws = (char*)d_ws;
  u16* wTq = (u16*)(ws + 0 * MB);   // [wTq;wTk;wTv] contiguous = fused QKV BT
  u16* wTk = (u16*)(ws + 2 * MB);
  u16* wTv = (u16*)(ws + 4 * MB);
  u16* wTo = (u16*)(ws + 6 * MB);
  u16* w1T = (u16*)(ws + 8 * MB);   // FF x D
  u16* w2T = (u16*)(ws + 16 * MB);  // D x FF (live through ffn2)
  u16* xb  = (u16*)(ws + 24 * MB);
  u16* qb  = (u16*)(ws + 32 * MB);
  u16* kb  = (u16*)(ws + 40 * MB);
  u16* vb  = (u16*)(ws + 48 * MB);
  u16* ao  = (u16*)(ws + 56 * MB);
  float* p0 = (float*)(ws + 64 * MB);    // proj partials (sk2): 64..96
  float* p1 = (float*)(ws + 80 * MB);
  float* x1f = (float*)(ws + 24 * MB);   // reuse xb+qb (dead after attn)
  u16*   x1b = (u16*)(ws + 40 * MB);     // reuse kb (dead after attn)
  u16*   h1  = (u16*)(ws + 48 * MB);     // 48..80 (vb/ao/p0 dead after LN1)
  float* f0 = (float*)(ws + 80 * MB);    // ffn2 partials (sk4)
  float* f1 = (float*)(ws + 96 * MB);
  float* f2 = (float*)(ws + 112 * MB);
  float* f3 = (float*)(ws + 0 * MB);     // weights 0..16 dead by ffn2 time

  // fused prep (x cvt + all 6 weight transposes) — 1 launch
  prep_kernel<<<dim3(16384), dim3(256), 0, stream>>>(
      x, xb, W1, w1T, W2, w2T, Wq, Wk, Wv, Wo, wTq, wTk, wTv, wTo);

  gemm_qkv<<<dim3(32, 24), dim3(256), 0, stream>>>(xb, wTq, bq, bk, bv, qb, kb, vb);

  attn_kernel<<<dim3(16, 32), dim3(256), 0, stream>>>(qb, kb, vb, mask, ao);

  // proj: split-K x2 (512 blocks), partials p0,p1
  gemm_bt_sk4<<<dim3(32, 8, 2), dim3(256), 0, stream>>>(
      ao, wTo, bo, p0, p1, p0, p0, 4096, 1024, 1024, 512);

  ln_kernel<<<dim3(4096), dim3(256), 0, stream>>>(x, p0, p1, g1, be1, x1f, x1b);

  gemm_bt_relu<<<dim3(32, 32), dim3(256), 0, stream>>>(x1b, w1T, b1, h1, 4096, 4096, 1024);

  // ffn2: split-K x4 (1024 blocks, 4/CU with launch_bounds), partials f0..f3
  gemm_bt_sk4<<<dim3(32, 8, 4), dim3(256), 0, stream>>>(
      h1, w2T, b2, f0, f1, f2, f3, 4096, 1024, 4096, 1024);

  ln4_kernel<<<dim3(4096), dim3(256), 0, stream>>>(
      x1f, f0, f1, f2, f3, g2, be2, (float*)d_out, (u16*)nullptr);
}

// Round 5
// 382.463 us; speedup vs baseline: 1.1109x; 1.1109x over previous
//
#include <hip/hip_runtime.h>
#include <stdint.h>
#include <stddef.h>

#define B_ 2
#define S_ 2048
#define D_ 1024
#define H_ 16
#define HD_ 64
#define FF_ 4096

typedef unsigned short u16;
typedef __attribute__((ext_vector_type(8))) short bf16x8;
typedef __attribute__((ext_vector_type(4))) float f32x4;

__device__ __forceinline__ u16 f2bf(float f) {
  unsigned u = __float_as_uint(f);
  u += 0x7fffu + ((u >> 16) & 1u);
  return (u16)(u >> 16);
}

__device__ __forceinline__ f32x4 mfma16(bf16x8 a, bf16x8 b, f32x4 c) {
  return __builtin_amdgcn_mfma_f32_16x16x32_bf16(a, b, c, 0, 0, 0);
}

__device__ __forceinline__ void gload16(const void* g, void* l) {
  __builtin_amdgcn_global_load_lds(
      (const __attribute__((address_space(1))) void*)g,
      (__attribute__((address_space(3))) void*)l, 16, 0, 0);
}

// XCD-aware block swizzle (bijective when gridDim.x % 8 == 0).
__device__ __forceinline__ void swizzle_mn(int& mt, int& nt) {
  int gm = gridDim.x;
  if ((gm & 7) == 0) {
    int bid = blockIdx.y * gm + blockIdx.x;
    int mper = gm >> 3;
    int xcd = bid & 7, idx = bid >> 3;
    mt = xcd * mper + (idx % mper);
    nt = idx / mper;
  } else {
    mt = blockIdx.x;
    nt = blockIdx.y;
  }
}

// ---------------- fused prep: x cvt + all weight transposes ----------------
// linear grid, bid-decoded:
//   [0,4096)      W1 transpose tiles (K=1024 x N=4096)
//   [4096,8192)   W2 transpose tiles (K=4096 x N=1024)
//   [8192,12288)  x fp32->bf16 (4096 blocks x 1024 elems)
//   [12288,16384) 4 x DxD transposes (Wq,Wk,Wv,Wo)
__global__ __launch_bounds__(256) void prep_kernel(
    const float* __restrict__ x, u16* __restrict__ xb,
    const float* __restrict__ W1, u16* __restrict__ w1T,
    const float* __restrict__ W2, u16* __restrict__ w2T,
    const float* __restrict__ Wq, const float* __restrict__ Wk,
    const float* __restrict__ Wv, const float* __restrict__ Wo,
    u16* __restrict__ wTq, u16* __restrict__ wTk,
    u16* __restrict__ wTv, u16* __restrict__ wTo) {
  int bid = blockIdx.x;
  int tid = threadIdx.x;
  if (bid >= 8192 && bid < 12288) {  // cvt path (no barrier)
    int i = (bid - 8192) * 1024 + tid * 4;
    float4 v = *(const float4*)(x + i);
    ushort4 o = { f2bf(v.x), f2bf(v.y), f2bf(v.z), f2bf(v.w) };
    *(ushort4*)(xb + i) = o;
    return;
  }
  const float* W;
  u16* WT;
  int K, N, k0, n0;
  if (bid < 4096) {  // W1
    W = W1; WT = w1T; K = 1024; N = 4096;
    k0 = (bid & 31) * 32; n0 = (bid >> 5) * 32;
  } else if (bid < 8192) {  // W2
    int b2 = bid - 4096;
    W = W2; WT = w2T; K = 4096; N = 1024;
    k0 = (b2 >> 5) * 32; n0 = (b2 & 31) * 32;
  } else {  // 4 x DxD
    int t = bid - 12288;
    int z = t >> 10, r = t & 1023;
    W = z == 0 ? Wq : (z == 1 ? Wk : (z == 2 ? Wv : Wo));
    WT = z == 0 ? wTq : (z == 1 ? wTk : (z == 2 ? wTv : wTo));
    K = 1024; N = 1024;
    k0 = (r & 31) * 32; n0 = (r >> 5) * 32;
  }
  __shared__ u16 t[32][33];
  int r = tid >> 3;
  int c = (tid & 7) << 2;
  float4 v = *(const float4*)(W + (size_t)(k0 + r) * N + n0 + c);
  t[r][c + 0] = f2bf(v.x); t[r][c + 1] = f2bf(v.y);
  t[r][c + 2] = f2bf(v.z); t[r][c + 3] = f2bf(v.w);
  __syncthreads();
  ushort4 o;
  o.x = t[c + 0][r]; o.y = t[c + 1][r]; o.z = t[c + 2][r]; o.w = t[c + 3][r];
  *(ushort4*)(WT + (size_t)(n0 + r) * K + k0 + c) = o;
}

// ---------------- GEMM 128x128, out bf16 + relu (+bias)  [ffn1] ------------
// launch_bounds(256,4): VGPR<=128 -> 4 blocks/CU -> 1024-block grid = 1 round
__global__ __launch_bounds__(256, 4) void gemm_bt_relu(
    const u16* __restrict__ A, const u16* __restrict__ BT,
    const float* __restrict__ bias, u16* __restrict__ outp,
    int M, int N, int K) {
  __shared__ __align__(16) u16 As[128 * 32];
  __shared__ __align__(16) u16 Bs[128 * 32];
  int tid = threadIdx.x;
  int lane = tid & 63;
  int wave = tid >> 6;
  int quad = lane >> 4;
  int l16 = lane & 15;
  int mt, nt;
  swizzle_mn(mt, nt);
  int m0 = mt * 128;
  int n0 = nt * 128;
  int wm = (wave >> 1) * 64;
  int wn = (wave & 1) * 64;

  f32x4 zero = {0.f, 0.f, 0.f, 0.f};
  f32x4 acc[4][4];
#pragma unroll
  for (int i = 0; i < 4; i++)
#pragma unroll
    for (int j = 0; j < 4; j++) acc[i][j] = zero;

  int c0 = tid, c1 = tid + 256;
  const u16* ga0 = A + (size_t)(m0 + (c0 >> 2)) * K + (c0 & 3) * 8;
  const u16* ga1 = A + (size_t)(m0 + (c1 >> 2)) * K + (c1 & 3) * 8;
  const u16* gb0 = BT + (size_t)(n0 + (c0 >> 2)) * K + (c0 & 3) * 8;
  const u16* gb1 = BT + (size_t)(n0 + (c1 >> 2)) * K + (c1 & 3) * 8;

  for (int k0 = 0; k0 < K; k0 += 32) {
    gload16(ga0 + k0, &As[c0 * 8]);
    gload16(ga1 + k0, &As[c1 * 8]);
    gload16(gb0 + k0, &Bs[c0 * 8]);
    gload16(gb1 + k0, &Bs[c1 * 8]);
    __syncthreads();
    bf16x8 af[4], bfr[4];
#pragma unroll
    for (int i = 0; i < 4; i++)
      af[i] = *(const bf16x8*)&As[(wm + i * 16 + l16) * 32 + quad * 8];
#pragma unroll
    for (int j = 0; j < 4; j++)
      bfr[j] = *(const bf16x8*)&Bs[(wn + j * 16 + l16) * 32 + quad * 8];
#pragma unroll
    for (int i = 0; i < 4; i++)
#pragma unroll
      for (int j = 0; j < 4; j++)
        acc[i][j] = mfma16(af[i], bfr[j], acc[i][j]);
    __syncthreads();
  }

#pragma unroll
  for (int j = 0; j < 4; j++) {
    int gcol = n0 + wn + j * 16 + l16;
    float bv = bias[gcol];
#pragma unroll
    for (int i = 0; i < 4; i++) {
#pragma unroll
      for (int r = 0; r < 4; r++) {
        int grow = m0 + wm + i * 16 + quad * 4 + r;
        float val = acc[i][j][r] + bv;
        outp[(size_t)grow * N + gcol] = f2bf(val > 0.f ? val : 0.f);
      }
    }
  }
}

// ---------------- GEMM 128x128 split-K (up to 4), separate fp32 outputs ----
__global__ __launch_bounds__(256, 4) void gemm_bt_sk4(
    const u16* __restrict__ A, const u16* __restrict__ BT,
    const float* __restrict__ bias,
    float* __restrict__ o0, float* __restrict__ o1,
    float* __restrict__ o2, float* __restrict__ o3,
    int M, int N, int K, int Kc) {
  __shared__ __align__(16) u16 As[128 * 32];
  __shared__ __align__(16) u16 Bs[128 * 32];
  int tid = threadIdx.x;
  int lane = tid & 63;
  int wave = tid >> 6;
  int quad = lane >> 4;
  int l16 = lane & 15;
  int mt, nt;
  swizzle_mn(mt, nt);
  int m0 = mt * 128;
  int n0 = nt * 128;
  int z = blockIdx.z;
  int kb = z * Kc;
  int wm = (wave >> 1) * 64;
  int wn = (wave & 1) * 64;

  f32x4 zero = {0.f, 0.f, 0.f, 0.f};
  f32x4 acc[4][4];
#pragma unroll
  for (int i = 0; i < 4; i++)
#pragma unroll
    for (int j = 0; j < 4; j++) acc[i][j] = zero;

  int c0 = tid, c1 = tid + 256;
  const u16* ga0 = A + (size_t)(m0 + (c0 >> 2)) * K + (c0 & 3) * 8 + kb;
  const u16* ga1 = A + (size_t)(m0 + (c1 >> 2)) * K + (c1 & 3) * 8 + kb;
  const u16* gb0 = BT + (size_t)(n0 + (c0 >> 2)) * K + (c0 & 3) * 8 + kb;
  const u16* gb1 = BT + (size_t)(n0 + (c1 >> 2)) * K + (c1 & 3) * 8 + kb;

  for (int k0 = 0; k0 < Kc; k0 += 32) {
    gload16(ga0 + k0, &As[c0 * 8]);
    gload16(ga1 + k0, &As[c1 * 8]);
    gload16(gb0 + k0, &Bs[c0 * 8]);
    gload16(gb1 + k0, &Bs[c1 * 8]);
    __syncthreads();
    bf16x8 af[4], bfr[4];
#pragma unroll
    for (int i = 0; i < 4; i++)
      af[i] = *(const bf16x8*)&As[(wm + i * 16 + l16) * 32 + quad * 8];
#pragma unroll
    for (int j = 0; j < 4; j++)
      bfr[j] = *(const bf16x8*)&Bs[(wn + j * 16 + l16) * 32 + quad * 8];
#pragma unroll
    for (int i = 0; i < 4; i++)
#pragma unroll
      for (int j = 0; j < 4; j++)
        acc[i][j] = mfma16(af[i], bfr[j], acc[i][j]);
    __syncthreads();
  }

  float* outz = z == 0 ? o0 : (z == 1 ? o1 : (z == 2 ? o2 : o3));
  float biasmul = (z == 0) ? 1.f : 0.f;
#pragma unroll
  for (int j = 0; j < 4; j++) {
    int gcol = n0 + wn + j * 16 + l16;
    float bv = bias[gcol] * biasmul;
#pragma unroll
    for (int i = 0; i < 4; i++) {
#pragma unroll
      for (int r = 0; r < 4; r++) {
        int grow = m0 + wm + i * 16 + quad * 4 + r;
        outz[(size_t)grow * N + gcol] = acc[i][j][r] + bv;
      }
    }
  }
}

// ---------------- fused QKV GEMM (q pre-scaled by 1/sqrt(HD)*log2e) --------
__global__ __launch_bounds__(256) void gemm_qkv(
    const u16* __restrict__ A, const u16* __restrict__ BT,
    const float* __restrict__ bq, const float* __restrict__ bk,
    const float* __restrict__ bvp,
    u16* __restrict__ qb, u16* __restrict__ kb, u16* __restrict__ vb) {
  const int K = 1024;
  __shared__ __align__(16) u16 As[128 * 32];
  __shared__ __align__(16) u16 Bs[128 * 32];
  int tid = threadIdx.x;
  int lane = tid & 63;
  int wave = tid >> 6;
  int quad = lane >> 4;
  int l16 = lane & 15;
  int mt, nt;
  swizzle_mn(mt, nt);
  int m0 = mt * 128;
  int n0 = nt * 128;
  int wm = (wave >> 1) * 64;
  int wn = (wave & 1) * 64;

  f32x4 zero = {0.f, 0.f, 0.f, 0.f};
  f32x4 acc[4][4];
#pragma unroll
  for (int i = 0; i < 4; i++)
#pragma unroll
    for (int j = 0; j < 4; j++) acc[i][j] = zero;

  int c0 = tid, c1 = tid + 256;
  const u16* ga0 = A + (size_t)(m0 + (c0 >> 2)) * K + (c0 & 3) * 8;
  const u16* ga1 = A + (size_t)(m0 + (c1 >> 2)) * K + (c1 & 3) * 8;
  const u16* gb0 = BT + (size_t)(n0 + (c0 >> 2)) * K + (c0 & 3) * 8;
  const u16* gb1 = BT + (size_t)(n0 + (c1 >> 2)) * K + (c1 & 3) * 8;

  for (int k0 = 0; k0 < K; k0 += 32) {
    gload16(ga0 + k0, &As[c0 * 8]);
    gload16(ga1 + k0, &As[c1 * 8]);
    gload16(gb0 + k0, &Bs[c0 * 8]);
    gload16(gb1 + k0, &Bs[c1 * 8]);
    __syncthreads();
    bf16x8 af[4], bfr[4];
#pragma unroll
    for (int i = 0; i < 4; i++)
      af[i] = *(const bf16x8*)&As[(wm + i * 16 + l16) * 32 + quad * 8];
#pragma unroll
    for (int j = 0; j < 4; j++)
      bfr[j] = *(const bf16x8*)&Bs[(wn + j * 16 + l16) * 32 + quad * 8];
#pragma unroll
    for (int i = 0; i < 4; i++)
#pragma unroll
      for (int j = 0; j < 4; j++)
        acc[i][j] = mfma16(af[i], bfr[j], acc[i][j]);
    __syncthreads();
  }

  int region = n0 >> 10;
  const float* bias = region == 0 ? bq : (region == 1 ? bk : bvp);
  u16* outp = region == 0 ? qb : (region == 1 ? kb : vb);
  float scale = region == 0 ? 0.125f * 1.4426950408889634f : 1.f;

#pragma unroll
  for (int j = 0; j < 4; j++) {
    int gcol = (n0 & 1023) + wn + j * 16 + l16;
    float bv = bias[gcol];
    int h = gcol >> 6, hd = gcol & 63;
#pragma unroll
    for (int i = 0; i < 4; i++) {
#pragma unroll
      for (int r = 0; r < 4; r++) {
        int grow = m0 + wm + i * 16 + quad * 4 + r;
        float val = (acc[i][j][r] + bv) * scale;
        int b = grow >> 11, s = grow & 2047;
        if (region < 2) {
          outp[(((size_t)(b * H_ + h)) * S_ + s) * HD_ + hd] = f2bf(val);
        } else {
          outp[(((size_t)(b * H_ + h)) * HD_ + hd) * S_ + s] = f2bf(val);
        }
      }
    }
  }
}

// ---------------- flash attention, K-split x2: MQ=32/wave, 4 blocks/CU -----
// R1 per-tile math/layouts retained exactly. Grid 1024 = 16 qt x 2 khalf x
// 32 bh (head-grouped per XCD: FETCH-validated). Single-buffered K/V
// (2-barrier loop, reg prefetch): LDS 36864 B -> 4 blocks/CU = 16 waves/CU.
// Outputs: unnormalized partial O (f32) + partial softmax sum l per half.
__global__ __launch_bounds__(256, 4) void attn_kernel(
    const u16* __restrict__ q, const u16* __restrict__ k,
    const u16* __restrict__ vt, const int* __restrict__ mask,
    float* __restrict__ po, float* __restrict__ pl) {
  __shared__ __align__(16) u16 Ks[64 * 72];
  __shared__ __align__(16) u16 Vs[64 * 72];
  __shared__ __align__(16) u16 Ps[4][32 * 72];
  int tid = threadIdx.x;
  int lane = tid & 63;
  int wave = tid >> 6;
  int quad = lane >> 4;
  int l16 = lane & 15;

  // decode: lin%8 -> XCD; per XCD: 16 qt x 2 half x 4 heads
  int lin = blockIdx.y * gridDim.x + blockIdx.x;  // 0..1023
  int xcd = lin & 7;
  int t = lin >> 3;         // 0..127
  int qt = t & 15;
  int half = (t >> 4) & 1;
  int hh = t >> 5;          // 0..3
  int bh = hh * 8 + xcd;
  int b = bh >> 4;
  int h = bh & 15;
  int qrow0 = qt * 128 + wave * 32;
  int kb = half * (S_ / 2);

  const u16* qh = q + (size_t)bh * S_ * HD_;
  const u16* kh = k + (size_t)bh * S_ * HD_;
  const u16* vh = vt + (size_t)bh * HD_ * S_;

  bf16x8 qfA0 = *(const bf16x8*)(qh + (size_t)(qrow0 + l16) * HD_ + quad * 8);
  bf16x8 qfA1 = *(const bf16x8*)(qh + (size_t)(qrow0 + l16) * HD_ + 32 + quad * 8);
  bf16x8 qfB0 = *(const bf16x8*)(qh + (size_t)(qrow0 + 16 + l16) * HD_ + quad * 8);
  bf16x8 qfB1 = *(const bf16x8*)(qh + (size_t)(qrow0 + 16 + l16) * HD_ + 32 + quad * 8);

  int sr = tid >> 3, sc = tid & 7;
  const u16* kg0 = kh + sr * HD_ + sc * 8;
  const u16* kg1 = kh + (sr + 32) * HD_ + sc * 8;
  const u16* vg0 = vh + (size_t)sr * S_ + sc * 8;
  const u16* vg1 = vh + (size_t)(sr + 32) * S_ + sc * 8;
  int kr0 = (sr & 1) * 16 + (sr >> 1);
  int ko0 = kr0 * 72 + sc * 8;
  int ko1 = (32 + kr0) * 72 + sc * 8;
  int vo0 = sr * 72 + sc * 8;
  int vo1 = (sr + 32) * 72 + sc * 8;
  const int* mrow = mask + b * S_ + 2 * l16;

  float l_pA[4] = {0.f, 0.f, 0.f, 0.f};
  float l_pB[4] = {0.f, 0.f, 0.f, 0.f};
  f32x4 zero = {0.f, 0.f, 0.f, 0.f};
  f32x4 o_accA[4], o_accB[4];
#pragma unroll
  for (int c = 0; c < 4; c++) { o_accA[c] = zero; o_accB[c] = zero; }

  u16* pw = &Ps[wave][0];

  // prologue: first tile -> regs
  bf16x8 kv0 = *(const bf16x8*)(kg0 + (size_t)kb * HD_);
  bf16x8 kv1 = *(const bf16x8*)(kg1 + (size_t)kb * HD_);
  bf16x8 vv0 = *(const bf16x8*)(vg0 + kb);
  bf16x8 vv1 = *(const bf16x8*)(vg1 + kb);

  for (int kt = kb; kt < kb + S_ / 2; kt += 64) {
    int2 mk0 = *(const int2*)(mrow + kt);
    int2 mk1 = *(const int2*)(mrow + kt + 32);

    __syncthreads();  // previous tile's compute done; Ks/Vs reusable
    *(bf16x8*)&Ks[ko0] = kv0;
    *(bf16x8*)&Ks[ko1] = kv1;
    *(bf16x8*)&Vs[vo0] = vv0;
    *(bf16x8*)&Vs[vo1] = vv1;
    if (kt + 64 < kb + S_ / 2) {
      int nk = kt + 64;
      kv0 = *(const bf16x8*)(kg0 + (size_t)nk * HD_);
      kv1 = *(const bf16x8*)(kg1 + (size_t)nk * HD_);
      vv0 = *(const bf16x8*)(vg0 + nk);
      vv1 = *(const bf16x8*)(vg1 + nk);
    }
    __syncthreads();  // staging visible

    const u16* ksb = &Ks[0];
    const u16* vsb = &Vs[0];
#pragma unroll
    for (int g = 0; g < 2; g++) {
      int2 mk = g == 0 ? mk0 : mk1;
      int rowe = (g * 32 + l16) * 72;
      int rowo = (g * 32 + 16 + l16) * 72;
      bf16x8 e0 = *(const bf16x8*)&ksb[rowe + quad * 8];
      bf16x8 e1 = *(const bf16x8*)&ksb[rowe + 32 + quad * 8];
      bf16x8 o0 = *(const bf16x8*)&ksb[rowo + quad * 8];
      bf16x8 o1 = *(const bf16x8*)&ksb[rowo + 32 + quad * 8];
      f32x4 seA = mfma16(qfA1, e1, mfma16(qfA0, e0, zero));
      f32x4 soA = mfma16(qfA1, o1, mfma16(qfA0, o0, zero));
      f32x4 seB = mfma16(qfB1, e1, mfma16(qfB0, e0, zero));
      f32x4 soB = mfma16(qfB1, o1, mfma16(qfB0, o0, zero));
#pragma unroll
      for (int r = 0; r < 4; r++) {
        float pA0 = mk.x ? exp2f(seA[r]) : 0.f;
        float pA1 = mk.y ? exp2f(soA[r]) : 0.f;
        float pB0 = mk.x ? exp2f(seB[r]) : 0.f;
        float pB1 = mk.y ? exp2f(soB[r]) : 0.f;
        l_pA[r] += pA0 + pA1;
        l_pB[r] += pB0 + pB1;
        unsigned pkA = __builtin_amdgcn_perm(__float_as_uint(pA1),
                                             __float_as_uint(pA0), 0x07060302u);
        unsigned pkB = __builtin_amdgcn_perm(__float_as_uint(pB1),
                                             __float_as_uint(pB0), 0x07060302u);
        *(unsigned*)&pw[(quad * 4 + r) * 72 + g * 32 + 2 * l16] = pkA;
        *(unsigned*)&pw[(16 + quad * 4 + r) * 72 + g * 32 + 2 * l16] = pkB;
      }
    }
    bf16x8 pfA0 = *(const bf16x8*)&pw[l16 * 72 + quad * 8];
    bf16x8 pfA1 = *(const bf16x8*)&pw[l16 * 72 + 32 + quad * 8];
    bf16x8 pfB0 = *(const bf16x8*)&pw[(16 + l16) * 72 + quad * 8];
    bf16x8 pfB1 = *(const bf16x8*)&pw[(16 + l16) * 72 + 32 + quad * 8];
#pragma unroll
    for (int c = 0; c < 4; c++) {
      bf16x8 vf0 = *(const bf16x8*)&vsb[(c * 16 + l16) * 72 + quad * 8];
      bf16x8 vf1 = *(const bf16x8*)&vsb[(c * 16 + l16) * 72 + 32 + quad * 8];
      o_accA[c] = mfma16(pfA1, vf1, mfma16(pfA0, vf0, o_accA[c]));
      o_accB[c] = mfma16(pfB1, vf1, mfma16(pfB0, vf0, o_accB[c]));
    }
  }

  float* poh = po + (size_t)half * ((size_t)B_ * S_ * D_);
  float* plh = pl + (size_t)half * ((size_t)B_ * H_ * S_);
#pragma unroll
  for (int r = 0; r < 4; r++) {
    float sA = l_pA[r], sB = l_pB[r];
#pragma unroll
    for (int off = 1; off < 16; off <<= 1) {
      sA += __shfl_xor(sA, off);
      sB += __shfl_xor(sB, off);
    }
    int srowA = qrow0 + quad * 4 + r;
    int srowB = qrow0 + 16 + quad * 4 + r;
    if (l16 == 0) {
      plh[(size_t)bh * S_ + srowA] = sA;
      plh[(size_t)bh * S_ + srowB] = sB;
    }
#pragma unroll
    for (int c = 0; c < 4; c++) {
      poh[((size_t)(b * S_ + srowA)) * D_ + h * HD_ + c * 16 + l16] =
          o_accA[c][r];
      poh[((size_t)(b * S_ + srowB)) * D_ + h * HD_ + c * 16 + l16] =
          o_accB[c][r];
    }
  }
}

// ---------------- combine K-split attention partials -> ao bf16 ------------
__global__ __launch_bounds__(256) void attn_combine(
    const float* __restrict__ po, const float* __restrict__ pl,
    u16* __restrict__ ao) {
  int row = blockIdx.x;  // b*S + s
  int tid = threadIdx.x;
  int b = row >> 11, s = row & 2047;
  int h = tid >> 4;  // (tid*4)>>6
  const size_t NPO = (size_t)B_ * S_ * D_;
  size_t off = (size_t)row * D_ + tid * 4;
  float4 o0 = *(const float4*)(po + off);
  float4 o1 = *(const float4*)(po + NPO + off);
  size_t li = ((size_t)(b * H_ + h)) * S_ + s;
  float l0 = pl[li], l1 = pl[(size_t)B_ * H_ * S_ + li];
  float inv = 1.f / (l0 + l1);
  ushort4 o = { f2bf((o0.x + o1.x) * inv), f2bf((o0.y + o1.y) * inv),
                f2bf((o0.z + o1.z) * inv), f2bf((o0.w + o1.w) * inv) };
  *(ushort4*)(ao + off) = o;
}

// ---------------- residual (2 partials) + layernorm ----------------
__global__ __launch_bounds__(256) void ln_kernel(
    const float* __restrict__ xa, const float* __restrict__ add0,
    const float* __restrict__ add1,
    const float* __restrict__ g, const float* __restrict__ be,
    float* __restrict__ outf, u16* __restrict__ outb) {
  int row = blockIdx.x;
  int tid = threadIdx.x;
  int lane = tid & 63;
  int wv = tid >> 6;
  const float4 a = *(const float4*)(xa + (size_t)row * D_ + tid * 4);
  const float4 c = *(const float4*)(add0 + (size_t)row * D_ + tid * 4);
  const float4 d = *(const float4*)(add1 + (size_t)row * D_ + tid * 4);
  float v0 = a.x + c.x + d.x, v1 = a.y + c.y + d.y;
  float v2 = a.z + c.z + d.z, v3 = a.w + c.w + d.w;
  float s = v0 + v1 + v2 + v3;
  float sq = v0 * v0 + v1 * v1 + v2 * v2 + v3 * v3;
#pragma unroll
  for (int off = 1; off < 64; off <<= 1) {
    s += __shfl_xor(s, off);
    sq += __shfl_xor(sq, off);
  }
  __shared__ float red[8];
  if (lane == 0) { red[wv] = s; red[4 + wv] = sq; }
  __syncthreads();
  s = red[0] + red[1] + red[2] + red[3];
  sq = red[4] + red[5] + red[6] + red[7];
  float mean = s * (1.f / D_);
  float var = sq * (1.f / D_) - mean * mean;
  float rstd = rsqrtf(var + 1e-5f);
  const float4 gv = *(const float4*)(g + tid * 4);
  const float4 bv = *(const float4*)(be + tid * 4);
  float y0 = (v0 - mean) * rstd * gv.x + bv.x;
  float y1 = (v1 - mean) * rstd * gv.y + bv.y;
  float y2 = (v2 - mean) * rstd * gv.z + bv.z;
  float y3 = (v3 - mean) * rstd * gv.w + bv.w;
  float4 o = {y0, y1, y2, y3};
  *(float4*)(outf + (size_t)row * D_ + tid * 4) = o;
  if (outb) {
    ushort4 ob = {f2bf(y0), f2bf(y1), f2bf(y2), f2bf(y3)};
    *(ushort4*)(outb + (size_t)row * D_ + tid * 4) = ob;
  }
}

// ---------------- residual (4 partials) + layernorm ----------------
__global__ __launch_bounds__(256) void ln4_kernel(
    const float* __restrict__ xa,
    const float* __restrict__ a0, const float* __restrict__ a1,
    const float* __restrict__ a2, const float* __restrict__ a3,
    const float* __restrict__ g, const float* __restrict__ be,
    float* __restrict__ outf, u16* __restrict__ outb) {
  int row = blockIdx.x;
  int tid = threadIdx.x;
  int lane = tid & 63;
  int wv = tid >> 6;
  size_t off0 = (size_t)row * D_ + tid * 4;
  const float4 a = *(const float4*)(xa + off0);
  const float4 c0 = *(const float4*)(a0 + off0);
  const float4 c1 = *(const float4*)(a1 + off0);
  const float4 c2 = *(const float4*)(a2 + off0);
  const float4 c3 = *(const float4*)(a3 + off0);
  float v0 = a.x + (c0.x + c1.x) + (c2.x + c3.x);
  float v1 = a.y + (c0.y + c1.y) + (c2.y + c3.y);
  float v2 = a.z + (c0.z + c1.z) + (c2.z + c3.z);
  float v3 = a.w + (c0.w + c1.w) + (c2.w + c3.w);
  float s = v0 + v1 + v2 + v3;
  float sq = v0 * v0 + v1 * v1 + v2 * v2 + v3 * v3;
#pragma unroll
  for (int off = 1; off < 64; off <<= 1) {
    s += __shfl_xor(s, off);
    sq += __shfl_xor(sq, off);
  }
  __shared__ float red[8];
  if (lane == 0) { red[wv] = s; red[4 + wv] = sq; }
  __syncthreads();
  s = red[0] + red[1] + red[2] + red[3];
  sq = red[4] + red[5] + red[6] + red[7];
  float mean = s * (1.f / D_);
  float var = sq * (1.f / D_) - mean * mean;
  float rstd = rsqrtf(var + 1e-5f);
  const float4 gv = *(const float4*)(g + tid * 4);
  const float4 bv = *(const float4*)(be + tid * 4);
  float y0 = (v0 - mean) * rstd * gv.x + bv.x;
  float y1 = (v1 - mean) * rstd * gv.y + bv.y;
  float y2 = (v2 - mean) * rstd * gv.z + bv.z;
  float y3 = (v3 - mean) * rstd * gv.w + bv.w;
  float4 o = {y0, y1, y2, y3};
  *(float4*)(outf + off0) = o;
  if (outb) {
    ushort4 ob = {f2bf(y0), f2bf(y1), f2bf(y2), f2bf(y3)};
    *(ushort4*)(outb + off0) = ob;
  }
}

extern "C" void kernel_launch(void* const* d_in, const int* in_sizes, int n_in,
                              void* d_out, int out_size, void* d_ws, size_t ws_size,
                              hipStream_t stream) {
  const float* x = (const float*)d_in[0];
  const int* mask = (const int*)d_in[1];
  const float* Wq = (const float*)d_in[2];
  const float* bq = (const float*)d_in[3];
  const float* Wk = (const float*)d_in[4];
  const float* bk = (const float*)d_in[5];
  const float* Wv = (const float*)d_in[6];
  const float* bv = (const float*)d_in[7];
  const float* Wo = (const float*)d_in[8];
  const float* bo = (const float*)d_in[9];
  const float* W1 = (const float*)d_in[10];
  const float* b1 = (const float*)d_in[11];
  const float* W2 = (const float*)d_in[12];
  const float* b2 = (const float*)d_in[13];
  const float* g1 = (const float*)d_in[14];
  const float* be1 = (const float*)d_in[15];
  const float* g2 = (const float*)d_in[16];
  const float* be2 = (const float*)d_in[17];

  const size_t MB = 1ull << 20;
  char* ws = (char*)d_ws;
  u16* wTq = (u16*)(ws + 0 * MB);   // [wTq;wTk;wTv] contiguous = fused QKV BT
  u16* wTk = (u16*)(ws + 2 * MB);
  u16* wTv = (u16*)(ws + 4 * MB);
  u16* wTo = (u16*)(ws + 6 * MB);
  u16* w1T = (u16*)(ws + 8 * MB);   // FF x D
  u16* w2T = (u16*)(ws + 16 * MB);  // D x FF (live through ffn2)
  u16* xb  = (u16*)(ws + 24 * MB);
  u16* qb  = (u16*)(ws + 32 * MB);
  u16* kb  = (u16*)(ws + 40 * MB);
  u16* vb  = (u16*)(ws + 48 * MB);
  u16* ao  = (u16*)(ws + 56 * MB);
  float* po = (float*)(ws + 64 * MB);    // attn partials f32: 64..96 (2x16MB)
  float* pl = (float*)(ws + 96 * MB);    // attn l partials: 96..96.5 (dead after combine)
  float* p0 = (float*)(ws + 64 * MB);    // proj partials (sk2), reuse po
  float* p1 = (float*)(ws + 80 * MB);
  float* x1f = (float*)(ws + 24 * MB);   // reuse xb+qb (dead after attn)
  u16*   x1b = (u16*)(ws + 40 * MB);     // reuse kb (dead after attn)
  u16*   h1  = (u16*)(ws + 48 * MB);     // 48..80 (vb/ao/p0 dead after LN1)
  float* f0 = (float*)(ws + 80 * MB);    // ffn2 partials (sk4): 80..96
  float* f1 = (float*)(ws + 96 * MB);    // 96..112 (pl dead by now)
  float* f2 = (float*)(ws + 112 * MB);   // 112..128
  float* f3 = (float*)(ws + 0 * MB);     // weights 0..16 dead by ffn2 time

  // fused prep (x cvt + all 6 weight transposes) — 1 launch
  prep_kernel<<<dim3(16384), dim3(256), 0, stream>>>(
      x, xb, W1, w1T, W2, w2T, Wq, Wk, Wv, Wo, wTq, wTk, wTv, wTo);

  gemm_qkv<<<dim3(32, 24), dim3(256), 0, stream>>>(xb, wTq, bq, bk, bv, qb, kb, vb);

  // K-split x2 attention: 1024 blocks, 4/CU
  attn_kernel<<<dim3(32, 32), dim3(256), 0, stream>>>(qb, kb, vb, mask, po, pl);

  attn_combine<<<dim3(4096), dim3(256), 0, stream>>>(po, pl, ao);

  // proj: split-K x2 (512 blocks), partials p0,p1 (overwrites po after combine)
  gemm_bt_sk4<<<dim3(32, 8, 2), dim3(256), 0, stream>>>(
      ao, wTo, bo, p0, p1, p0, p0, 4096, 1024, 1024, 512);

  ln_kernel<<<dim3(4096), dim3(256), 0, stream>>>(x, p0, p1, g1, be1, x1f, x1b);

  gemm_bt_relu<<<dim3(32, 32), dim3(256), 0, stream>>>(x1b, w1T, b1, h1, 4096, 4096, 1024);

  // ffn2: split-K x4 (1024 blocks, 4/CU with launch_bounds), partials f0..f3
  gemm_bt_sk4<<<dim3(32, 8, 4), dim3(256), 0, stream>>>(
      h1, w2T, b2, f0, f1, f2, f3, 4096, 1024, 4096, 1024);

  ln4_kernel<<<dim3(4096), dim3(256), 0, stream>>>(
      x1f, f0, f1, f2, f3, g2, be2, (float*)d_out, (u16*)nullptr);
}

// Round 6
// 372.142 us; speedup vs baseline: 1.1417x; 1.0277x over previous
//
#include <hip/hip_runtime.h>
#include <stdint.h>
#include <stddef.h>

#define B_ 2
#define S_ 2048
#define D_ 1024
#define H_ 16
#define HD_ 64
#define FF_ 4096

typedef unsigned short u16;
typedef __attribute__((ext_vector_type(8))) short bf16x8;
typedef __attribute__((ext_vector_type(4))) float f32x4;

__device__ __forceinline__ u16 f2bf(float f) {
  unsigned u = __float_as_uint(f);
  u += 0x7fffu + ((u >> 16) & 1u);
  return (u16)(u >> 16);
}

__device__ __forceinline__ f32x4 mfma16(bf16x8 a, bf16x8 b, f32x4 c) {
  return __builtin_amdgcn_mfma_f32_16x16x32_bf16(a, b, c, 0, 0, 0);
}

__device__ __forceinline__ void gload16(const void* g, void* l) {
  __builtin_amdgcn_global_load_lds(
      (const __attribute__((address_space(1))) void*)g,
      (__attribute__((address_space(3))) void*)l, 16, 0, 0);
}

// XCD-aware block swizzle (bijective when gridDim.x % 8 == 0).
__device__ __forceinline__ void swizzle_mn(int& mt, int& nt) {
  int gm = gridDim.x;
  if ((gm & 7) == 0) {
    int bid = blockIdx.y * gm + blockIdx.x;
    int mper = gm >> 3;
    int xcd = bid & 7, idx = bid >> 3;
    mt = xcd * mper + (idx % mper);
    nt = idx / mper;
  } else {
    mt = blockIdx.x;
    nt = blockIdx.y;
  }
}

// ---------------- fused prep: x cvt + all weight transposes ----------------
__global__ __launch_bounds__(256) void prep_kernel(
    const float* __restrict__ x, u16* __restrict__ xb,
    const float* __restrict__ W1, u16* __restrict__ w1T,
    const float* __restrict__ W2, u16* __restrict__ w2T,
    const float* __restrict__ Wq, const float* __restrict__ Wk,
    const float* __restrict__ Wv, const float* __restrict__ Wo,
    u16* __restrict__ wTq, u16* __restrict__ wTk,
    u16* __restrict__ wTv, u16* __restrict__ wTo) {
  int bid = blockIdx.x;
  int tid = threadIdx.x;
  if (bid >= 8192 && bid < 12288) {  // cvt path (no barrier)
    int i = (bid - 8192) * 1024 + tid * 4;
    float4 v = *(const float4*)(x + i);
    ushort4 o = { f2bf(v.x), f2bf(v.y), f2bf(v.z), f2bf(v.w) };
    *(ushort4*)(xb + i) = o;
    return;
  }
  const float* W;
  u16* WT;
  int K, N, k0, n0;
  if (bid < 4096) {  // W1
    W = W1; WT = w1T; K = 1024; N = 4096;
    k0 = (bid & 31) * 32; n0 = (bid >> 5) * 32;
  } else if (bid < 8192) {  // W2
    int b2 = bid - 4096;
    W = W2; WT = w2T; K = 4096; N = 1024;
    k0 = (b2 >> 5) * 32; n0 = (b2 & 31) * 32;
  } else {  // 4 x DxD
    int t = bid - 12288;
    int z = t >> 10, r = t & 1023;
    W = z == 0 ? Wq : (z == 1 ? Wk : (z == 2 ? Wv : Wo));
    WT = z == 0 ? wTq : (z == 1 ? wTk : (z == 2 ? wTv : wTo));
    K = 1024; N = 1024;
    k0 = (r & 31) * 32; n0 = (r >> 5) * 32;
  }
  __shared__ u16 t[32][33];
  int r = tid >> 3;
  int c = (tid & 7) << 2;
  float4 v = *(const float4*)(W + (size_t)(k0 + r) * N + n0 + c);
  t[r][c + 0] = f2bf(v.x); t[r][c + 1] = f2bf(v.y);
  t[r][c + 2] = f2bf(v.z); t[r][c + 3] = f2bf(v.w);
  __syncthreads();
  ushort4 o;
  o.x = t[c + 0][r]; o.y = t[c + 1][r]; o.z = t[c + 2][r]; o.w = t[c + 3][r];
  *(ushort4*)(WT + (size_t)(n0 + r) * K + k0 + c) = o;
}

// ---------------- GEMM 128x128 BK=64 (2x 128x32 sub-buffers/operand) -------
// out bf16 + relu (+bias)  [ffn1]; halved barrier count vs BK=32.
__global__ __launch_bounds__(256, 4) void gemm_bt_relu(
    const u16* __restrict__ A, const u16* __restrict__ BT,
    const float* __restrict__ bias, u16* __restrict__ outp,
    int M, int N, int K) {
  __shared__ __align__(16) u16 As[2][128 * 32];
  __shared__ __align__(16) u16 Bs[2][128 * 32];
  int tid = threadIdx.x;
  int lane = tid & 63;
  int wave = tid >> 6;
  int quad = lane >> 4;
  int l16 = lane & 15;
  int mt, nt;
  swizzle_mn(mt, nt);
  int m0 = mt * 128;
  int n0 = nt * 128;
  int wm = (wave >> 1) * 64;
  int wn = (wave & 1) * 64;

  f32x4 zero = {0.f, 0.f, 0.f, 0.f};
  f32x4 acc[4][4];
#pragma unroll
  for (int i = 0; i < 4; i++)
#pragma unroll
    for (int j = 0; j < 4; j++) acc[i][j] = zero;

  int c0 = tid, c1 = tid + 256;
  const u16* ga0 = A + (size_t)(m0 + (c0 >> 2)) * K + (c0 & 3) * 8;
  const u16* ga1 = A + (size_t)(m0 + (c1 >> 2)) * K + (c1 & 3) * 8;
  const u16* gb0 = BT + (size_t)(n0 + (c0 >> 2)) * K + (c0 & 3) * 8;
  const u16* gb1 = BT + (size_t)(n0 + (c1 >> 2)) * K + (c1 & 3) * 8;

  for (int k0 = 0; k0 < K; k0 += 64) {
#pragma unroll
    for (int h = 0; h < 2; h++) {
      int kk = k0 + h * 32;
      gload16(ga0 + kk, &As[h][c0 * 8]);
      gload16(ga1 + kk, &As[h][c1 * 8]);
      gload16(gb0 + kk, &Bs[h][c0 * 8]);
      gload16(gb1 + kk, &Bs[h][c1 * 8]);
    }
    __syncthreads();
#pragma unroll
    for (int h = 0; h < 2; h++) {
      bf16x8 af[4], bfr[4];
#pragma unroll
      for (int i = 0; i < 4; i++)
        af[i] = *(const bf16x8*)&As[h][(wm + i * 16 + l16) * 32 + quad * 8];
#pragma unroll
      for (int j = 0; j < 4; j++)
        bfr[j] = *(const bf16x8*)&Bs[h][(wn + j * 16 + l16) * 32 + quad * 8];
#pragma unroll
      for (int i = 0; i < 4; i++)
#pragma unroll
        for (int j = 0; j < 4; j++)
          acc[i][j] = mfma16(af[i], bfr[j], acc[i][j]);
    }
    __syncthreads();
  }

#pragma unroll
  for (int j = 0; j < 4; j++) {
    int gcol = n0 + wn + j * 16 + l16;
    float bv = bias[gcol];
#pragma unroll
    for (int i = 0; i < 4; i++) {
#pragma unroll
      for (int r = 0; r < 4; r++) {
        int grow = m0 + wm + i * 16 + quad * 4 + r;
        float val = acc[i][j][r] + bv;
        outp[(size_t)grow * N + gcol] = f2bf(val > 0.f ? val : 0.f);
      }
    }
  }
}

// ---------------- GEMM 128x128 BK=64 split-K (up to 4), fp32 outputs -------
__global__ __launch_bounds__(256, 4) void gemm_bt_sk4(
    const u16* __restrict__ A, const u16* __restrict__ BT,
    const float* __restrict__ bias,
    float* __restrict__ o0, float* __restrict__ o1,
    float* __restrict__ o2, float* __restrict__ o3,
    int M, int N, int K, int Kc) {
  __shared__ __align__(16) u16 As[2][128 * 32];
  __shared__ __align__(16) u16 Bs[2][128 * 32];
  int tid = threadIdx.x;
  int lane = tid & 63;
  int wave = tid >> 6;
  int quad = lane >> 4;
  int l16 = lane & 15;
  int mt, nt;
  swizzle_mn(mt, nt);
  int m0 = mt * 128;
  int n0 = nt * 128;
  int z = blockIdx.z;
  int kb = z * Kc;
  int wm = (wave >> 1) * 64;
  int wn = (wave & 1) * 64;

  f32x4 zero = {0.f, 0.f, 0.f, 0.f};
  f32x4 acc[4][4];
#pragma unroll
  for (int i = 0; i < 4; i++)
#pragma unroll
    for (int j = 0; j < 4; j++) acc[i][j] = zero;

  int c0 = tid, c1 = tid + 256;
  const u16* ga0 = A + (size_t)(m0 + (c0 >> 2)) * K + (c0 & 3) * 8 + kb;
  const u16* ga1 = A + (size_t)(m0 + (c1 >> 2)) * K + (c1 & 3) * 8 + kb;
  const u16* gb0 = BT + (size_t)(n0 + (c0 >> 2)) * K + (c0 & 3) * 8 + kb;
  const u16* gb1 = BT + (size_t)(n0 + (c1 >> 2)) * K + (c1 & 3) * 8 + kb;

  for (int k0 = 0; k0 < Kc; k0 += 64) {
#pragma unroll
    for (int h = 0; h < 2; h++) {
      int kk = k0 + h * 32;
      gload16(ga0 + kk, &As[h][c0 * 8]);
      gload16(ga1 + kk, &As[h][c1 * 8]);
      gload16(gb0 + kk, &Bs[h][c0 * 8]);
      gload16(gb1 + kk, &Bs[h][c1 * 8]);
    }
    __syncthreads();
#pragma unroll
    for (int h = 0; h < 2; h++) {
      bf16x8 af[4], bfr[4];
#pragma unroll
      for (int i = 0; i < 4; i++)
        af[i] = *(const bf16x8*)&As[h][(wm + i * 16 + l16) * 32 + quad * 8];
#pragma unroll
      for (int j = 0; j < 4; j++)
        bfr[j] = *(const bf16x8*)&Bs[h][(wn + j * 16 + l16) * 32 + quad * 8];
#pragma unroll
      for (int i = 0; i < 4; i++)
#pragma unroll
        for (int j = 0; j < 4; j++)
          acc[i][j] = mfma16(af[i], bfr[j], acc[i][j]);
    }
    __syncthreads();
  }

  float* outz = z == 0 ? o0 : (z == 1 ? o1 : (z == 2 ? o2 : o3));
  float biasmul = (z == 0) ? 1.f : 0.f;
#pragma unroll
  for (int j = 0; j < 4; j++) {
    int gcol = n0 + wn + j * 16 + l16;
    float bv = bias[gcol] * biasmul;
#pragma unroll
    for (int i = 0; i < 4; i++) {
#pragma unroll
      for (int r = 0; r < 4; r++) {
        int grow = m0 + wm + i * 16 + quad * 4 + r;
        outz[(size_t)grow * N + gcol] = acc[i][j][r] + bv;
      }
    }
  }
}

// ---------------- fused QKV GEMM BK=64 (q pre-scaled by 1/sqrt(HD)*log2e) --
__global__ __launch_bounds__(256, 4) void gemm_qkv(
    const u16* __restrict__ A, const u16* __restrict__ BT,
    const float* __restrict__ bq, const float* __restrict__ bk,
    const float* __restrict__ bvp,
    u16* __restrict__ qb, u16* __restrict__ kb, u16* __restrict__ vb) {
  const int K = 1024;
  __shared__ __align__(16) u16 As[2][128 * 32];
  __shared__ __align__(16) u16 Bs[2][128 * 32];
  int tid = threadIdx.x;
  int lane = tid & 63;
  int wave = tid >> 6;
  int quad = lane >> 4;
  int l16 = lane & 15;
  int mt, nt;
  swizzle_mn(mt, nt);
  int m0 = mt * 128;
  int n0 = nt * 128;
  int wm = (wave >> 1) * 64;
  int wn = (wave & 1) * 64;

  f32x4 zero = {0.f, 0.f, 0.f, 0.f};
  f32x4 acc[4][4];
#pragma unroll
  for (int i = 0; i < 4; i++)
#pragma unroll
    for (int j = 0; j < 4; j++) acc[i][j] = zero;

  int c0 = tid, c1 = tid + 256;
  const u16* ga0 = A + (size_t)(m0 + (c0 >> 2)) * K + (c0 & 3) * 8;
  const u16* ga1 = A + (size_t)(m0 + (c1 >> 2)) * K + (c1 & 3) * 8;
  const u16* gb0 = BT + (size_t)(n0 + (c0 >> 2)) * K + (c0 & 3) * 8;
  const u16* gb1 = BT + (size_t)(n0 + (c1 >> 2)) * K + (c1 & 3) * 8;

  for (int k0 = 0; k0 < K; k0 += 64) {
#pragma unroll
    for (int h = 0; h < 2; h++) {
      int kk = k0 + h * 32;
      gload16(ga0 + kk, &As[h][c0 * 8]);
      gload16(ga1 + kk, &As[h][c1 * 8]);
      gload16(gb0 + kk, &Bs[h][c0 * 8]);
      gload16(gb1 + kk, &Bs[h][c1 * 8]);
    }
    __syncthreads();
#pragma unroll
    for (int h = 0; h < 2; h++) {
      bf16x8 af[4], bfr[4];
#pragma unroll
      for (int i = 0; i < 4; i++)
        af[i] = *(const bf16x8*)&As[h][(wm + i * 16 + l16) * 32 + quad * 8];
#pragma unroll
      for (int j = 0; j < 4; j++)
        bfr[j] = *(const bf16x8*)&Bs[h][(wn + j * 16 + l16) * 32 + quad * 8];
#pragma unroll
      for (int i = 0; i < 4; i++)
#pragma unroll
        for (int j = 0; j < 4; j++)
          acc[i][j] = mfma16(af[i], bfr[j], acc[i][j]);
    }
    __syncthreads();
  }

  int region = n0 >> 10;
  const float* bias = region == 0 ? bq : (region == 1 ? bk : bvp);
  u16* outp = region == 0 ? qb : (region == 1 ? kb : vb);
  float scale = region == 0 ? 0.125f * 1.4426950408889634f : 1.f;

#pragma unroll
  for (int j = 0; j < 4; j++) {
    int gcol = (n0 & 1023) + wn + j * 16 + l16;
    float bv = bias[gcol];
    int h = gcol >> 6, hd = gcol & 63;
#pragma unroll
    for (int i = 0; i < 4; i++) {
#pragma unroll
      for (int r = 0; r < 4; r++) {
        int grow = m0 + wm + i * 16 + quad * 4 + r;
        float val = (acc[i][j][r] + bv) * scale;
        int b = grow >> 11, s = grow & 2047;
        if (region < 2) {
          outp[(((size_t)(b * H_ + h)) * S_ + s) * HD_ + hd] = f2bf(val);
        } else {
          outp[(((size_t)(b * H_ + h)) * HD_ + hd) * S_ + s] = f2bf(val);
        }
      }
    }
  }
}

// ---------------- flash attention: MQ=32/wave, double-buffered K/V ---------
// (exact R1 kernel — known 75 us; occupancy levers exhausted R2/R3/R5)
__global__ __launch_bounds__(256, 2) void attn_kernel(
    const u16* __restrict__ q, const u16* __restrict__ k,
    const u16* __restrict__ vt, const int* __restrict__ mask,
    u16* __restrict__ ao) {
  __shared__ __align__(16) u16 Ks[2][64 * 72];
  __shared__ __align__(16) u16 Vs[2][64 * 72];
  __shared__ __align__(16) u16 Ps[4][32 * 72];
  int tid = threadIdx.x;
  int lane = tid & 63;
  int wave = tid >> 6;
  int quad = lane >> 4;
  int l16 = lane & 15;
  int bh = blockIdx.y;
  int b = bh >> 4;
  int h = bh & 15;
  int qrow0 = blockIdx.x * 128 + wave * 32;

  const u16* qh = q + (size_t)bh * S_ * HD_;
  const u16* kh = k + (size_t)bh * S_ * HD_;
  const u16* vh = vt + (size_t)bh * HD_ * S_;

  bf16x8 qfA0 = *(const bf16x8*)(qh + (size_t)(qrow0 + l16) * HD_ + quad * 8);
  bf16x8 qfA1 = *(const bf16x8*)(qh + (size_t)(qrow0 + l16) * HD_ + 32 + quad * 8);
  bf16x8 qfB0 = *(const bf16x8*)(qh + (size_t)(qrow0 + 16 + l16) * HD_ + quad * 8);
  bf16x8 qfB1 = *(const bf16x8*)(qh + (size_t)(qrow0 + 16 + l16) * HD_ + 32 + quad * 8);

  int sr = tid >> 3, sc = tid & 7;
  const u16* kg0 = kh + sr * HD_ + sc * 8;
  const u16* kg1 = kh + (sr + 32) * HD_ + sc * 8;
  const u16* vg0 = vh + (size_t)sr * S_ + sc * 8;
  const u16* vg1 = vh + (size_t)(sr + 32) * S_ + sc * 8;
  int kr0 = (sr & 1) * 16 + (sr >> 1);
  int ko0 = kr0 * 72 + sc * 8;
  int ko1 = (32 + kr0) * 72 + sc * 8;
  int vo0 = sr * 72 + sc * 8;
  int vo1 = (sr + 32) * 72 + sc * 8;
  const int* mrow = mask + b * S_ + 2 * l16;

  float l_pA[4] = {0.f, 0.f, 0.f, 0.f};
  float l_pB[4] = {0.f, 0.f, 0.f, 0.f};
  f32x4 zero = {0.f, 0.f, 0.f, 0.f};
  f32x4 o_accA[4], o_accB[4];
#pragma unroll
  for (int c = 0; c < 4; c++) { o_accA[c] = zero; o_accB[c] = zero; }

  u16* pw = &Ps[wave][0];

  bf16x8 kv0 = *(const bf16x8*)(kg0);
  bf16x8 kv1 = *(const bf16x8*)(kg1);
  bf16x8 vv0 = *(const bf16x8*)(vg0);
  bf16x8 vv1 = *(const bf16x8*)(vg1);
  *(bf16x8*)&Ks[0][ko0] = kv0;
  *(bf16x8*)&Ks[0][ko1] = kv1;
  *(bf16x8*)&Vs[0][vo0] = vv0;
  *(bf16x8*)&Vs[0][vo1] = vv1;
  kv0 = *(const bf16x8*)(kg0 + (size_t)64 * HD_);
  kv1 = *(const bf16x8*)(kg1 + (size_t)64 * HD_);
  vv0 = *(const bf16x8*)(vg0 + 64);
  vv1 = *(const bf16x8*)(vg1 + 64);

  int cur = 0;
  for (int kt = 0; kt < S_; kt += 64) {
    int2 mk0 = *(const int2*)(mrow + kt);
    int2 mk1 = *(const int2*)(mrow + kt + 32);

    __syncthreads();
    if (kt + 64 < S_) {
      int alt = cur ^ 1;
      *(bf16x8*)&Ks[alt][ko0] = kv0;
      *(bf16x8*)&Ks[alt][ko1] = kv1;
      *(bf16x8*)&Vs[alt][vo0] = vv0;
      *(bf16x8*)&Vs[alt][vo1] = vv1;
      int nk = (kt + 128) & (S_ - 1);
      kv0 = *(const bf16x8*)(kg0 + (size_t)nk * HD_);
      kv1 = *(const bf16x8*)(kg1 + (size_t)nk * HD_);
      vv0 = *(const bf16x8*)(vg0 + nk);
      vv1 = *(const bf16x8*)(vg1 + nk);
    }

    const u16* ksb = &Ks[cur][0];
    const u16* vsb = &Vs[cur][0];
#pragma unroll
    for (int g = 0; g < 2; g++) {
      int2 mk = g == 0 ? mk0 : mk1;
      int rowe = (g * 32 + l16) * 72;
      int rowo = (g * 32 + 16 + l16) * 72;
      bf16x8 e0 = *(const bf16x8*)&ksb[rowe + quad * 8];
      bf16x8 e1 = *(const bf16x8*)&ksb[rowe + 32 + quad * 8];
      bf16x8 o0 = *(const bf16x8*)&ksb[rowo + quad * 8];
      bf16x8 o1 = *(const bf16x8*)&ksb[rowo + 32 + quad * 8];
      f32x4 seA = mfma16(qfA1, e1, mfma16(qfA0, e0, zero));
      f32x4 soA = mfma16(qfA1, o1, mfma16(qfA0, o0, zero));
      f32x4 seB = mfma16(qfB1, e1, mfma16(qfB0, e0, zero));
      f32x4 soB = mfma16(qfB1, o1, mfma16(qfB0, o0, zero));
#pragma unroll
      for (int r = 0; r < 4; r++) {
        float pA0 = mk.x ? exp2f(seA[r]) : 0.f;
        float pA1 = mk.y ? exp2f(soA[r]) : 0.f;
        float pB0 = mk.x ? exp2f(seB[r]) : 0.f;
        float pB1 = mk.y ? exp2f(soB[r]) : 0.f;
        l_pA[r] += pA0 + pA1;
        l_pB[r] += pB0 + pB1;
        unsigned pkA = __builtin_amdgcn_perm(__float_as_uint(pA1),
                                             __float_as_uint(pA0), 0x07060302u);
        unsigned pkB = __builtin_amdgcn_perm(__float_as_uint(pB1),
                                             __float_as_uint(pB0), 0x07060302u);
        *(unsigned*)&pw[(quad * 4 + r) * 72 + g * 32 + 2 * l16] = pkA;
        *(unsigned*)&pw[(16 + quad * 4 + r) * 72 + g * 32 + 2 * l16] = pkB;
      }
    }
    bf16x8 pfA0 = *(const bf16x8*)&pw[l16 * 72 + quad * 8];
    bf16x8 pfA1 = *(const bf16x8*)&pw[l16 * 72 + 32 + quad * 8];
    bf16x8 pfB0 = *(const bf16x8*)&pw[(16 + l16) * 72 + quad * 8];
    bf16x8 pfB1 = *(const bf16x8*)&pw[(16 + l16) * 72 + 32 + quad * 8];
#pragma unroll
    for (int c = 0; c < 4; c++) {
      bf16x8 vf0 = *(const bf16x8*)&vsb[(c * 16 + l16) * 72 + quad * 8];
      bf16x8 vf1 = *(const bf16x8*)&vsb[(c * 16 + l16) * 72 + 32 + quad * 8];
      o_accA[c] = mfma16(pfA1, vf1, mfma16(pfA0, vf0, o_accA[c]));
      o_accB[c] = mfma16(pfB1, vf1, mfma16(pfB0, vf0, o_accB[c]));
    }
    cur ^= 1;
  }

#pragma unroll
  for (int r = 0; r < 4; r++) {
    float sA = l_pA[r], sB = l_pB[r];
#pragma unroll
    for (int off = 1; off < 16; off <<= 1) {
      sA += __shfl_xor(sA, off);
      sB += __shfl_xor(sB, off);
    }
    float invA = 1.f / sA, invB = 1.f / sB;
    int srowA = qrow0 + quad * 4 + r;
    int srowB = qrow0 + 16 + quad * 4 + r;
#pragma unroll
    for (int c = 0; c < 4; c++) {
      ao[((size_t)(b * S_ + srowA)) * D_ + h * HD_ + c * 16 + l16] =
          f2bf(o_accA[c][r] * invA);
      ao[((size_t)(b * S_ + srowB)) * D_ + h * HD_ + c * 16 + l16] =
          f2bf(o_accB[c][r] * invB);
    }
  }
}

// ---------------- residual (2 partials) + layernorm ----------------
__global__ __launch_bounds__(256) void ln_kernel(
    const float* __restrict__ xa, const float* __restrict__ add0,
    const float* __restrict__ add1,
    const float* __restrict__ g, const float* __restrict__ be,
    float* __restrict__ outf, u16* __restrict__ outb) {
  int row = blockIdx.x;
  int tid = threadIdx.x;
  int lane = tid & 63;
  int wv = tid >> 6;
  const float4 a = *(const float4*)(xa + (size_t)row * D_ + tid * 4);
  const float4 c = *(const float4*)(add0 + (size_t)row * D_ + tid * 4);
  const float4 d = *(const float4*)(add1 + (size_t)row * D_ + tid * 4);
  float v0 = a.x + c.x + d.x, v1 = a.y + c.y + d.y;
  float v2 = a.z + c.z + d.z, v3 = a.w + c.w + d.w;
  float s = v0 + v1 + v2 + v3;
  float sq = v0 * v0 + v1 * v1 + v2 * v2 + v3 * v3;
#pragma unroll
  for (int off = 1; off < 64; off <<= 1) {
    s += __shfl_xor(s, off);
    sq += __shfl_xor(sq, off);
  }
  __shared__ float red[8];
  if (lane == 0) { red[wv] = s; red[4 + wv] = sq; }
  __syncthreads();
  s = red[0] + red[1] + red[2] + red[3];
  sq = red[4] + red[5] + red[6] + red[7];
  float mean = s * (1.f / D_);
  float var = sq * (1.f / D_) - mean * mean;
  float rstd = rsqrtf(var + 1e-5f);
  const float4 gv = *(const float4*)(g + tid * 4);
  const float4 bv = *(const float4*)(be + tid * 4);
  float y0 = (v0 - mean) * rstd * gv.x + bv.x;
  float y1 = (v1 - mean) * rstd * gv.y + bv.y;
  float y2 = (v2 - mean) * rstd * gv.z + bv.z;
  float y3 = (v3 - mean) * rstd * gv.w + bv.w;
  float4 o = {y0, y1, y2, y3};
  *(float4*)(outf + (size_t)row * D_ + tid * 4) = o;
  if (outb) {
    ushort4 ob = {f2bf(y0), f2bf(y1), f2bf(y2), f2bf(y3)};
    *(ushort4*)(outb + (size_t)row * D_ + tid * 4) = ob;
  }
}

// ---------------- residual (4 partials) + layernorm ----------------
__global__ __launch_bounds__(256) void ln4_kernel(
    const float* __restrict__ xa,
    const float* __restrict__ a0, const float* __restrict__ a1,
    const float* __restrict__ a2, const float* __restrict__ a3,
    const float* __restrict__ g, const float* __restrict__ be,
    float* __restrict__ outf, u16* __restrict__ outb) {
  int row = blockIdx.x;
  int tid = threadIdx.x;
  int lane = tid & 63;
  int wv = tid >> 6;
  size_t off0 = (size_t)row * D_ + tid * 4;
  const float4 a = *(const float4*)(xa + off0);
  const float4 c0 = *(const float4*)(a0 + off0);
  const float4 c1 = *(const float4*)(a1 + off0);
  const float4 c2 = *(const float4*)(a2 + off0);
  const float4 c3 = *(const float4*)(a3 + off0);
  float v0 = a.x + (c0.x + c1.x) + (c2.x + c3.x);
  float v1 = a.y + (c0.y + c1.y) + (c2.y + c3.y);
  float v2 = a.z + (c0.z + c1.z) + (c2.z + c3.z);
  float v3 = a.w + (c0.w + c1.w) + (c2.w + c3.w);
  float s = v0 + v1 + v2 + v3;
  float sq = v0 * v0 + v1 * v1 + v2 * v2 + v3 * v3;
#pragma unroll
  for (int off = 1; off < 64; off <<= 1) {
    s += __shfl_xor(s, off);
    sq += __shfl_xor(sq, off);
  }
  __shared__ float red[8];
  if (lane == 0) { red[wv] = s; red[4 + wv] = sq; }
  __syncthreads();
  s = red[0] + red[1] + red[2] + red[3];
  sq = red[4] + red[5] + red[6] + red[7];
  float mean = s * (1.f / D_);
  float var = sq * (1.f / D_) - mean * mean;
  float rstd = rsqrtf(var + 1e-5f);
  const float4 gv = *(const float4*)(g + tid * 4);
  const float4 bv = *(const float4*)(be + tid * 4);
  float y0 = (v0 - mean) * rstd * gv.x + bv.x;
  float y1 = (v1 - mean) * rstd * gv.y + bv.y;
  float y2 = (v2 - mean) * rstd * gv.z + bv.z;
  float y3 = (v3 - mean) * rstd * gv.w + bv.w;
  float4 o = {y0, y1, y2, y3};
  *(float4*)(outf + off0) = o;
  if (outb) {
    ushort4 ob = {f2bf(y0), f2bf(y1), f2bf(y2), f2bf(y3)};
    *(ushort4*)(outb + off0) = ob;
  }
}

extern "C" void kernel_launch(void* const* d_in, const int* in_sizes, int n_in,
                              void* d_out, int out_size, void* d_ws, size_t ws_size,
                              hipStream_t stream) {
  const float* x = (const float*)d_in[0];
  const int* mask = (const int*)d_in[1];
  const float* Wq = (const float*)d_in[2];
  const float* bq = (const float*)d_in[3];
  const float* Wk = (const float*)d_in[4];
  const float* bk = (const float*)d_in[5];
  const float* Wv = (const float*)d_in[6];
  const float* bv = (const float*)d_in[7];
  const float* Wo = (const float*)d_in[8];
  const float* bo = (const float*)d_in[9];
  const float* W1 = (const float*)d_in[10];
  const float* b1 = (const float*)d_in[11];
  const float* W2 = (const float*)d_in[12];
  const float* b2 = (const float*)d_in[13];
  const float* g1 = (const float*)d_in[14];
  const float* be1 = (const float*)d_in[15];
  const float* g2 = (const float*)d_in[16];
  const float* be2 = (const float*)d_in[17];

  const size_t MB = 1ull << 20;
  char* ws = (char*)d_ws;
  u16* wTq = (u16*)(ws + 0 * MB);   // [wTq;wTk;wTv] contiguous = fused QKV BT
  u16* wTk = (u16*)(ws + 2 * MB);
  u16* wTv = (u16*)(ws + 4 * MB);
  u16* wTo = (u16*)(ws + 6 * MB);
  u16* w1T = (u16*)(ws + 8 * MB);   // FF x D
  u16* w2T = (u16*)(ws + 16 * MB);  // D x FF (live through ffn2)
  u16* xb  = (u16*)(ws + 24 * MB);
  u16* qb  = (u16*)(ws + 32 * MB);
  u16* kb  = (u16*)(ws + 40 * MB);
  u16* vb  = (u16*)(ws + 48 * MB);
  u16* ao  = (u16*)(ws + 56 * MB);
  float* p0 = (float*)(ws + 64 * MB);    // proj partials (sk2): 64..96
  float* p1 = (float*)(ws + 80 * MB);
  float* x1f = (float*)(ws + 24 * MB);   // reuse xb+qb (dead after attn)
  u16*   x1b = (u16*)(ws + 40 * MB);     // reuse kb (dead after attn)
  u16*   h1  = (u16*)(ws + 48 * MB);     // 48..80 (vb/ao/p0 dead after LN1)
  float* f0 = (float*)(ws + 80 * MB);    // ffn2 partials (sk4)
  float* f1 = (float*)(ws + 96 * MB);
  float* f2 = (float*)(ws + 112 * MB);
  float* f3 = (float*)(ws + 0 * MB);     // weights 0..16 dead by ffn2 time

  // fused prep (x cvt + all 6 weight transposes) — 1 launch
  prep_kernel<<<dim3(16384), dim3(256), 0, stream>>>(
      x, xb, W1, w1T, W2, w2T, Wq, Wk, Wv, Wo, wTq, wTk, wTv, wTo);

  gemm_qkv<<<dim3(32, 24), dim3(256), 0, stream>>>(xb, wTq, bq, bk, bv, qb, kb, vb);

  attn_kernel<<<dim3(S_ / 128, B_ * H_), dim3(256), 0, stream>>>(qb, kb, vb, mask, ao);

  // proj: split-K x2 (512 blocks), partials p0,p1
  gemm_bt_sk4<<<dim3(32, 8, 2), dim3(256), 0, stream>>>(
      ao, wTo, bo, p0, p1, p0, p0, 4096, 1024, 1024, 512);

  ln_kernel<<<dim3(4096), dim3(256), 0, stream>>>(x, p0, p1, g1, be1, x1f, x1b);

  gemm_bt_relu<<<dim3(32, 32), dim3(256), 0, stream>>>(x1b, w1T, b1, h1, 4096, 4096, 1024);

  // ffn2: split-K x4 (1024 blocks, 4/CU with launch_bounds), partials f0..f3
  gemm_bt_sk4<<<dim3(32, 8, 4), dim3(256), 0, stream>>>(
      h1, w2T, b2, f0, f1, f2, f3, 4096, 1024, 4096, 1024);

  ln4_kernel<<<dim3(4096), dim3(256), 0, stream>>>(
      x1f, f0, f1, f2, f3, g2, be2, (float*)d_out, (u16*)nullptr);
}

// Round 7
// 370.522 us; speedup vs baseline: 1.1467x; 1.0044x over previous
//
#include <hip/hip_runtime.h>
#include <stdint.h>
#include <stddef.h>

#define B_ 2
#define S_ 2048
#define D_ 1024
#define H_ 16
#define HD_ 64
#define FF_ 4096

typedef unsigned short u16;
typedef __attribute__((ext_vector_type(8))) short bf16x8;
typedef __attribute__((ext_vector_type(4))) float f32x4;

__device__ __forceinline__ u16 f2bf(float f) {
  unsigned u = __float_as_uint(f);
  u += 0x7fffu + ((u >> 16) & 1u);
  return (u16)(u >> 16);
}

__device__ __forceinline__ f32x4 mfma16(bf16x8 a, bf16x8 b, f32x4 c) {
  return __builtin_amdgcn_mfma_f32_16x16x32_bf16(a, b, c, 0, 0, 0);
}

__device__ __forceinline__ void gload16(const void* g, void* l) {
  __builtin_amdgcn_global_load_lds(
      (const __attribute__((address_space(1))) void*)g,
      (__attribute__((address_space(3))) void*)l, 16, 0, 0);
}

// XCD-aware block swizzle (bijective when gridDim.x % 8 == 0).
__device__ __forceinline__ void swizzle_mn(int& mt, int& nt) {
  int gm = gridDim.x;
  if ((gm & 7) == 0) {
    int bid = blockIdx.y * gm + blockIdx.x;
    int mper = gm >> 3;
    int xcd = bid & 7, idx = bid >> 3;
    mt = xcd * mper + (idx % mper);
    nt = idx / mper;
  } else {
    mt = blockIdx.x;
    nt = blockIdx.y;
  }
}

// ---------------- fused prep: x cvt + all weight transposes ----------------
__global__ __launch_bounds__(256) void prep_kernel(
    const float* __restrict__ x, u16* __restrict__ xb,
    const float* __restrict__ W1, u16* __restrict__ w1T,
    const float* __restrict__ W2, u16* __restrict__ w2T,
    const float* __restrict__ Wq, const float* __restrict__ Wk,
    const float* __restrict__ Wv, const float* __restrict__ Wo,
    u16* __restrict__ wTq, u16* __restrict__ wTk,
    u16* __restrict__ wTv, u16* __restrict__ wTo) {
  int bid = blockIdx.x;
  int tid = threadIdx.x;
  if (bid >= 8192 && bid < 12288) {  // cvt path (no barrier)
    int i = (bid - 8192) * 1024 + tid * 4;
    float4 v = *(const float4*)(x + i);
    ushort4 o = { f2bf(v.x), f2bf(v.y), f2bf(v.z), f2bf(v.w) };
    *(ushort4*)(xb + i) = o;
    return;
  }
  const float* W;
  u16* WT;
  int K, N, k0, n0;
  if (bid < 4096) {  // W1
    W = W1; WT = w1T; K = 1024; N = 4096;
    k0 = (bid & 31) * 32; n0 = (bid >> 5) * 32;
  } else if (bid < 8192) {  // W2
    int b2 = bid - 4096;
    W = W2; WT = w2T; K = 4096; N = 1024;
    k0 = (b2 >> 5) * 32; n0 = (b2 & 31) * 32;
  } else {  // 4 x DxD
    int t = bid - 12288;
    int z = t >> 10, r = t & 1023;
    W = z == 0 ? Wq : (z == 1 ? Wk : (z == 2 ? Wv : Wo));
    WT = z == 0 ? wTq : (z == 1 ? wTk : (z == 2 ? wTv : wTo));
    K = 1024; N = 1024;
    k0 = (r & 31) * 32; n0 = (r >> 5) * 32;
  }
  __shared__ u16 t[32][33];
  int r = tid >> 3;
  int c = (tid & 7) << 2;
  float4 v = *(const float4*)(W + (size_t)(k0 + r) * N + n0 + c);
  t[r][c + 0] = f2bf(v.x); t[r][c + 1] = f2bf(v.y);
  t[r][c + 2] = f2bf(v.z); t[r][c + 3] = f2bf(v.w);
  __syncthreads();
  ushort4 o;
  o.x = t[c + 0][r]; o.y = t[c + 1][r]; o.z = t[c + 2][r]; o.w = t[c + 3][r];
  *(ushort4*)(WT + (size_t)(n0 + r) * K + k0 + c) = o;
}

// ======== 2-phase GEMM macros: stage(next)->compute(cur)->barrier ==========
// (T3-minimum recipe: loads fly during MFMA phase; one barrier per K-step)
#define GEMM_STAGE(BUF, KK)                      \
  do {                                           \
    gload16(ga0 + (KK), &As[BUF][c0 * 8]);       \
    gload16(ga1 + (KK), &As[BUF][c1 * 8]);       \
    gload16(gb0 + (KK), &Bs[BUF][c0 * 8]);       \
    gload16(gb1 + (KK), &Bs[BUF][c1 * 8]);       \
  } while (0)

#define GEMM_COMPUTE(BUF)                                                   \
  do {                                                                      \
    bf16x8 af[4], bfr[4];                                                   \
    _Pragma("unroll") for (int i = 0; i < 4; i++)                           \
        af[i] = *(const bf16x8*)&As[BUF][(wm + i * 16 + l16) * 32 + quad * 8]; \
    _Pragma("unroll") for (int j = 0; j < 4; j++)                           \
        bfr[j] = *(const bf16x8*)&Bs[BUF][(wn + j * 16 + l16) * 32 + quad * 8]; \
    _Pragma("unroll") for (int i = 0; i < 4; i++)                           \
        _Pragma("unroll") for (int j = 0; j < 4; j++)                       \
            acc[i][j] = mfma16(af[i], bfr[j], acc[i][j]);                   \
  } while (0)

// ---------------- GEMM 128x128 BK=32 2-phase, out bf16+relu [ffn1] ---------
__global__ __launch_bounds__(256, 4) void gemm_bt_relu(
    const u16* __restrict__ A, const u16* __restrict__ BT,
    const float* __restrict__ bias, u16* __restrict__ outp,
    int M, int N, int K) {
  __shared__ __align__(16) u16 As[2][128 * 32];
  __shared__ __align__(16) u16 Bs[2][128 * 32];
  int tid = threadIdx.x;
  int lane = tid & 63;
  int wave = tid >> 6;
  int quad = lane >> 4;
  int l16 = lane & 15;
  int mt, nt;
  swizzle_mn(mt, nt);
  int m0 = mt * 128;
  int n0 = nt * 128;
  int wm = (wave >> 1) * 64;
  int wn = (wave & 1) * 64;

  f32x4 zero = {0.f, 0.f, 0.f, 0.f};
  f32x4 acc[4][4];
#pragma unroll
  for (int i = 0; i < 4; i++)
#pragma unroll
    for (int j = 0; j < 4; j++) acc[i][j] = zero;

  int c0 = tid, c1 = tid + 256;
  const u16* ga0 = A + (size_t)(m0 + (c0 >> 2)) * K + (c0 & 3) * 8;
  const u16* ga1 = A + (size_t)(m0 + (c1 >> 2)) * K + (c1 & 3) * 8;
  const u16* gb0 = BT + (size_t)(n0 + (c0 >> 2)) * K + (c0 & 3) * 8;
  const u16* gb1 = BT + (size_t)(n0 + (c1 >> 2)) * K + (c1 & 3) * 8;

  GEMM_STAGE(0, 0);
  __syncthreads();
  for (int k0 = 0; k0 < K; k0 += 64) {
    if (k0 + 32 < K) GEMM_STAGE(1, k0 + 32);
    GEMM_COMPUTE(0);
    __syncthreads();
    if (k0 + 64 < K) GEMM_STAGE(0, k0 + 64);
    GEMM_COMPUTE(1);
    __syncthreads();
  }

#pragma unroll
  for (int j = 0; j < 4; j++) {
    int gcol = n0 + wn + j * 16 + l16;
    float bv = bias[gcol];
#pragma unroll
    for (int i = 0; i < 4; i++) {
#pragma unroll
      for (int r = 0; r < 4; r++) {
        int grow = m0 + wm + i * 16 + quad * 4 + r;
        float val = acc[i][j][r] + bv;
        outp[(size_t)grow * N + gcol] = f2bf(val > 0.f ? val : 0.f);
      }
    }
  }
}

// ---------------- GEMM 128x128 BK=32 2-phase split-K (up to 4) -------------
__global__ __launch_bounds__(256, 4) void gemm_bt_sk4(
    const u16* __restrict__ A, const u16* __restrict__ BT,
    const float* __restrict__ bias,
    float* __restrict__ o0, float* __restrict__ o1,
    float* __restrict__ o2, float* __restrict__ o3,
    int M, int N, int K, int Kc) {
  __shared__ __align__(16) u16 As[2][128 * 32];
  __shared__ __align__(16) u16 Bs[2][128 * 32];
  int tid = threadIdx.x;
  int lane = tid & 63;
  int wave = tid >> 6;
  int quad = lane >> 4;
  int l16 = lane & 15;
  int mt, nt;
  swizzle_mn(mt, nt);
  int m0 = mt * 128;
  int n0 = nt * 128;
  int z = blockIdx.z;
  int kb = z * Kc;
  int wm = (wave >> 1) * 64;
  int wn = (wave & 1) * 64;

  f32x4 zero = {0.f, 0.f, 0.f, 0.f};
  f32x4 acc[4][4];
#pragma unroll
  for (int i = 0; i < 4; i++)
#pragma unroll
    for (int j = 0; j < 4; j++) acc[i][j] = zero;

  int c0 = tid, c1 = tid + 256;
  const u16* ga0 = A + (size_t)(m0 + (c0 >> 2)) * K + (c0 & 3) * 8 + kb;
  const u16* ga1 = A + (size_t)(m0 + (c1 >> 2)) * K + (c1 & 3) * 8 + kb;
  const u16* gb0 = BT + (size_t)(n0 + (c0 >> 2)) * K + (c0 & 3) * 8 + kb;
  const u16* gb1 = BT + (size_t)(n0 + (c1 >> 2)) * K + (c1 & 3) * 8 + kb;

  GEMM_STAGE(0, 0);
  __syncthreads();
  for (int k0 = 0; k0 < Kc; k0 += 64) {
    if (k0 + 32 < Kc) GEMM_STAGE(1, k0 + 32);
    GEMM_COMPUTE(0);
    __syncthreads();
    if (k0 + 64 < Kc) GEMM_STAGE(0, k0 + 64);
    GEMM_COMPUTE(1);
    __syncthreads();
  }

  float* outz = z == 0 ? o0 : (z == 1 ? o1 : (z == 2 ? o2 : o3));
  float biasmul = (z == 0) ? 1.f : 0.f;
#pragma unroll
  for (int j = 0; j < 4; j++) {
    int gcol = n0 + wn + j * 16 + l16;
    float bv = bias[gcol] * biasmul;
#pragma unroll
    for (int i = 0; i < 4; i++) {
#pragma unroll
      for (int r = 0; r < 4; r++) {
        int grow = m0 + wm + i * 16 + quad * 4 + r;
        outz[(size_t)grow * N + gcol] = acc[i][j][r] + bv;
      }
    }
  }
}

// ---------------- fused QKV GEMM BK=32 2-phase -----------------------------
__global__ __launch_bounds__(256, 4) void gemm_qkv(
    const u16* __restrict__ A, const u16* __restrict__ BT,
    const float* __restrict__ bq, const float* __restrict__ bk,
    const float* __restrict__ bvp,
    u16* __restrict__ qb, u16* __restrict__ kb, u16* __restrict__ vb) {
  const int K = 1024;
  __shared__ __align__(16) u16 As[2][128 * 32];
  __shared__ __align__(16) u16 Bs[2][128 * 32];
  int tid = threadIdx.x;
  int lane = tid & 63;
  int wave = tid >> 6;
  int quad = lane >> 4;
  int l16 = lane & 15;
  int mt, nt;
  swizzle_mn(mt, nt);
  int m0 = mt * 128;
  int n0 = nt * 128;
  int wm = (wave >> 1) * 64;
  int wn = (wave & 1) * 64;

  f32x4 zero = {0.f, 0.f, 0.f, 0.f};
  f32x4 acc[4][4];
#pragma unroll
  for (int i = 0; i < 4; i++)
#pragma unroll
    for (int j = 0; j < 4; j++) acc[i][j] = zero;

  int c0 = tid, c1 = tid + 256;
  const u16* ga0 = A + (size_t)(m0 + (c0 >> 2)) * K + (c0 & 3) * 8;
  const u16* ga1 = A + (size_t)(m0 + (c1 >> 2)) * K + (c1 & 3) * 8;
  const u16* gb0 = BT + (size_t)(n0 + (c0 >> 2)) * K + (c0 & 3) * 8;
  const u16* gb1 = BT + (size_t)(n0 + (c1 >> 2)) * K + (c1 & 3) * 8;

  GEMM_STAGE(0, 0);
  __syncthreads();
  for (int k0 = 0; k0 < K; k0 += 64) {
    if (k0 + 32 < K) GEMM_STAGE(1, k0 + 32);
    GEMM_COMPUTE(0);
    __syncthreads();
    if (k0 + 64 < K) GEMM_STAGE(0, k0 + 64);
    GEMM_COMPUTE(1);
    __syncthreads();
  }

  int region = n0 >> 10;
  const float* bias = region == 0 ? bq : (region == 1 ? bk : bvp);
  u16* outp = region == 0 ? qb : (region == 1 ? kb : vb);
  float scale = region == 0 ? 0.125f * 1.4426950408889634f : 1.f;

#pragma unroll
  for (int j = 0; j < 4; j++) {
    int gcol = (n0 & 1023) + wn + j * 16 + l16;
    float bv = bias[gcol];
    int h = gcol >> 6, hd = gcol & 63;
#pragma unroll
    for (int i = 0; i < 4; i++) {
#pragma unroll
      for (int r = 0; r < 4; r++) {
        int grow = m0 + wm + i * 16 + quad * 4 + r;
        float val = (acc[i][j][r] + bv) * scale;
        int b = grow >> 11, s = grow & 2047;
        if (region < 2) {
          outp[(((size_t)(b * H_ + h)) * S_ + s) * HD_ + hd] = f2bf(val);
        } else {
          outp[(((size_t)(b * H_ + h)) * HD_ + hd) * S_ + s] = f2bf(val);
        }
      }
    }
  }
}

// ---------------- flash attention: MQ=32/wave, double-buffered K/V ---------
// (exact R1 kernel — known 73 us)
__global__ __launch_bounds__(256, 2) void attn_kernel(
    const u16* __restrict__ q, const u16* __restrict__ k,
    const u16* __restrict__ vt, const int* __restrict__ mask,
    u16* __restrict__ ao) {
  __shared__ __align__(16) u16 Ks[2][64 * 72];
  __shared__ __align__(16) u16 Vs[2][64 * 72];
  __shared__ __align__(16) u16 Ps[4][32 * 72];
  int tid = threadIdx.x;
  int lane = tid & 63;
  int wave = tid >> 6;
  int quad = lane >> 4;
  int l16 = lane & 15;
  int bh = blockIdx.y;
  int b = bh >> 4;
  int h = bh & 15;
  int qrow0 = blockIdx.x * 128 + wave * 32;

  const u16* qh = q + (size_t)bh * S_ * HD_;
  const u16* kh = k + (size_t)bh * S_ * HD_;
  const u16* vh = vt + (size_t)bh * HD_ * S_;

  bf16x8 qfA0 = *(const bf16x8*)(qh + (size_t)(qrow0 + l16) * HD_ + quad * 8);
  bf16x8 qfA1 = *(const bf16x8*)(qh + (size_t)(qrow0 + l16) * HD_ + 32 + quad * 8);
  bf16x8 qfB0 = *(const bf16x8*)(qh + (size_t)(qrow0 + 16 + l16) * HD_ + quad * 8);
  bf16x8 qfB1 = *(const bf16x8*)(qh + (size_t)(qrow0 + 16 + l16) * HD_ + 32 + quad * 8);

  int sr = tid >> 3, sc = tid & 7;
  const u16* kg0 = kh + sr * HD_ + sc * 8;
  const u16* kg1 = kh + (sr + 32) * HD_ + sc * 8;
  const u16* vg0 = vh + (size_t)sr * S_ + sc * 8;
  const u16* vg1 = vh + (size_t)(sr + 32) * S_ + sc * 8;
  int kr0 = (sr & 1) * 16 + (sr >> 1);
  int ko0 = kr0 * 72 + sc * 8;
  int ko1 = (32 + kr0) * 72 + sc * 8;
  int vo0 = sr * 72 + sc * 8;
  int vo1 = (sr + 32) * 72 + sc * 8;
  const int* mrow = mask + b * S_ + 2 * l16;

  float l_pA[4] = {0.f, 0.f, 0.f, 0.f};
  float l_pB[4] = {0.f, 0.f, 0.f, 0.f};
  f32x4 zero = {0.f, 0.f, 0.f, 0.f};
  f32x4 o_accA[4], o_accB[4];
#pragma unroll
  for (int c = 0; c < 4; c++) { o_accA[c] = zero; o_accB[c] = zero; }

  u16* pw = &Ps[wave][0];

  bf16x8 kv0 = *(const bf16x8*)(kg0);
  bf16x8 kv1 = *(const bf16x8*)(kg1);
  bf16x8 vv0 = *(const bf16x8*)(vg0);
  bf16x8 vv1 = *(const bf16x8*)(vg1);
  *(bf16x8*)&Ks[0][ko0] = kv0;
  *(bf16x8*)&Ks[0][ko1] = kv1;
  *(bf16x8*)&Vs[0][vo0] = vv0;
  *(bf16x8*)&Vs[0][vo1] = vv1;
  kv0 = *(const bf16x8*)(kg0 + (size_t)64 * HD_);
  kv1 = *(const bf16x8*)(kg1 + (size_t)64 * HD_);
  vv0 = *(const bf16x8*)(vg0 + 64);
  vv1 = *(const bf16x8*)(vg1 + 64);

  int cur = 0;
  for (int kt = 0; kt < S_; kt += 64) {
    int2 mk0 = *(const int2*)(mrow + kt);
    int2 mk1 = *(const int2*)(mrow + kt + 32);

    __syncthreads();
    if (kt + 64 < S_) {
      int alt = cur ^ 1;
      *(bf16x8*)&Ks[alt][ko0] = kv0;
      *(bf16x8*)&Ks[alt][ko1] = kv1;
      *(bf16x8*)&Vs[alt][vo0] = vv0;
      *(bf16x8*)&Vs[alt][vo1] = vv1;
      int nk = (kt + 128) & (S_ - 1);
      kv0 = *(const bf16x8*)(kg0 + (size_t)nk * HD_);
      kv1 = *(const bf16x8*)(kg1 + (size_t)nk * HD_);
      vv0 = *(const bf16x8*)(vg0 + nk);
      vv1 = *(const bf16x8*)(vg1 + nk);
    }

    const u16* ksb = &Ks[cur][0];
    const u16* vsb = &Vs[cur][0];
#pragma unroll
    for (int g = 0; g < 2; g++) {
      int2 mk = g == 0 ? mk0 : mk1;
      int rowe = (g * 32 + l16) * 72;
      int rowo = (g * 32 + 16 + l16) * 72;
      bf16x8 e0 = *(const bf16x8*)&ksb[rowe + quad * 8];
      bf16x8 e1 = *(const bf16x8*)&ksb[rowe + 32 + quad * 8];
      bf16x8 o0 = *(const bf16x8*)&ksb[rowo + quad * 8];
      bf16x8 o1 = *(const bf16x8*)&ksb[rowo + 32 + quad * 8];
      f32x4 seA = mfma16(qfA1, e1, mfma16(qfA0, e0, zero));
      f32x4 soA = mfma16(qfA1, o1, mfma16(qfA0, o0, zero));
      f32x4 seB = mfma16(qfB1, e1, mfma16(qfB0, e0, zero));
      f32x4 soB = mfma16(qfB1, o1, mfma16(qfB0, o0, zero));
#pragma unroll
      for (int r = 0; r < 4; r++) {
        float pA0 = mk.x ? exp2f(seA[r]) : 0.f;
        float pA1 = mk.y ? exp2f(soA[r]) : 0.f;
        float pB0 = mk.x ? exp2f(seB[r]) : 0.f;
        float pB1 = mk.y ? exp2f(soB[r]) : 0.f;
        l_pA[r] += pA0 + pA1;
        l_pB[r] += pB0 + pB1;
        unsigned pkA = __builtin_amdgcn_perm(__float_as_uint(pA1),
                                             __float_as_uint(pA0), 0x07060302u);
        unsigned pkB = __builtin_amdgcn_perm(__float_as_uint(pB1),
                                             __float_as_uint(pB0), 0x07060302u);
        *(unsigned*)&pw[(quad * 4 + r) * 72 + g * 32 + 2 * l16] = pkA;
        *(unsigned*)&pw[(16 + quad * 4 + r) * 72 + g * 32 + 2 * l16] = pkB;
      }
    }
    bf16x8 pfA0 = *(const bf16x8*)&pw[l16 * 72 + quad * 8];
    bf16x8 pfA1 = *(const bf16x8*)&pw[l16 * 72 + 32 + quad * 8];
    bf16x8 pfB0 = *(const bf16x8*)&pw[(16 + l16) * 72 + quad * 8];
    bf16x8 pfB1 = *(const bf16x8*)&pw[(16 + l16) * 72 + 32 + quad * 8];
#pragma unroll
    for (int c = 0; c < 4; c++) {
      bf16x8 vf0 = *(const bf16x8*)&vsb[(c * 16 + l16) * 72 + quad * 8];
      bf16x8 vf1 = *(const bf16x8*)&vsb[(c * 16 + l16) * 72 + 32 + quad * 8];
      o_accA[c] = mfma16(pfA1, vf1, mfma16(pfA0, vf0, o_accA[c]));
      o_accB[c] = mfma16(pfB1, vf1, mfma16(pfB0, vf0, o_accB[c]));
    }
    cur ^= 1;
  }

#pragma unroll
  for (int r = 0; r < 4; r++) {
    float sA = l_pA[r], sB = l_pB[r];
#pragma unroll
    for (int off = 1; off < 16; off <<= 1) {
      sA += __shfl_xor(sA, off);
      sB += __shfl_xor(sB, off);
    }
    float invA = 1.f / sA, invB = 1.f / sB;
    int srowA = qrow0 + quad * 4 + r;
    int srowB = qrow0 + 16 + quad * 4 + r;
#pragma unroll
    for (int c = 0; c < 4; c++) {
      ao[((size_t)(b * S_ + srowA)) * D_ + h * HD_ + c * 16 + l16] =
          f2bf(o_accA[c][r] * invA);
      ao[((size_t)(b * S_ + srowB)) * D_ + h * HD_ + c * 16 + l16] =
          f2bf(o_accB[c][r] * invB);
    }
  }
}

// ---------------- residual (2 partials) + layernorm ----------------
__global__ __launch_bounds__(256) void ln_kernel(
    const float* __restrict__ xa, const float* __restrict__ add0,
    const float* __restrict__ add1,
    const float* __restrict__ g, const float* __restrict__ be,
    float* __restrict__ outf, u16* __restrict__ outb) {
  int row = blockIdx.x;
  int tid = threadIdx.x;
  int lane = tid & 63;
  int wv = tid >> 6;
  const float4 a = *(const float4*)(xa + (size_t)row * D_ + tid * 4);
  const float4 c = *(const float4*)(add0 + (size_t)row * D_ + tid * 4);
  const float4 d = *(const float4*)(add1 + (size_t)row * D_ + tid * 4);
  float v0 = a.x + c.x + d.x, v1 = a.y + c.y + d.y;
  float v2 = a.z + c.z + d.z, v3 = a.w + c.w + d.w;
  float s = v0 + v1 + v2 + v3;
  float sq = v0 * v0 + v1 * v1 + v2 * v2 + v3 * v3;
#pragma unroll
  for (int off = 1; off < 64; off <<= 1) {
    s += __shfl_xor(s, off);
    sq += __shfl_xor(sq, off);
  }
  __shared__ float red[8];
  if (lane == 0) { red[wv] = s; red[4 + wv] = sq; }
  __syncthreads();
  s = red[0] + red[1] + red[2] + red[3];
  sq = red[4] + red[5] + red[6] + red[7];
  float mean = s * (1.f / D_);
  float var = sq * (1.f / D_) - mean * mean;
  float rstd = rsqrtf(var + 1e-5f);
  const float4 gv = *(const float4*)(g + tid * 4);
  const float4 bv = *(const float4*)(be + tid * 4);
  float y0 = (v0 - mean) * rstd * gv.x + bv.x;
  float y1 = (v1 - mean) * rstd * gv.y + bv.y;
  float y2 = (v2 - mean) * rstd * gv.z + bv.z;
  float y3 = (v3 - mean) * rstd * gv.w + bv.w;
  float4 o = {y0, y1, y2, y3};
  *(float4*)(outf + (size_t)row * D_ + tid * 4) = o;
  if (outb) {
    ushort4 ob = {f2bf(y0), f2bf(y1), f2bf(y2), f2bf(y3)};
    *(ushort4*)(outb + (size_t)row * D_ + tid * 4) = ob;
  }
}

// ---------------- residual (4 partials) + layernorm ----------------
__global__ __launch_bounds__(256) void ln4_kernel(
    const float* __restrict__ xa,
    const float* __restrict__ a0, const float* __restrict__ a1,
    const float* __restrict__ a2, const float* __restrict__ a3,
    const float* __restrict__ g, const float* __restrict__ be,
    float* __restrict__ outf, u16* __restrict__ outb) {
  int row = blockIdx.x;
  int tid = threadIdx.x;
  int lane = tid & 63;
  int wv = tid >> 6;
  size_t off0 = (size_t)row * D_ + tid * 4;
  const float4 a = *(const float4*)(xa + off0);
  const float4 c0 = *(const float4*)(a0 + off0);
  const float4 c1 = *(const float4*)(a1 + off0);
  const float4 c2 = *(const float4*)(a2 + off0);
  const float4 c3 = *(const float4*)(a3 + off0);
  float v0 = a.x + (c0.x + c1.x) + (c2.x + c3.x);
  float v1 = a.y + (c0.y + c1.y) + (c2.y + c3.y);
  float v2 = a.z + (c0.z + c1.z) + (c2.z + c3.z);
  float v3 = a.w + (c0.w + c1.w) + (c2.w + c3.w);
  float s = v0 + v1 + v2 + v3;
  float sq = v0 * v0 + v1 * v1 + v2 * v2 + v3 * v3;
#pragma unroll
  for (int off = 1; off < 64; off <<= 1) {
    s += __shfl_xor(s, off);
    sq += __shfl_xor(sq, off);
  }
  __shared__ float red[8];
  if (lane == 0) { red[wv] = s; red[4 + wv] = sq; }
  __syncthreads();
  s = red[0] + red[1] + red[2] + red[3];
  sq = red[4] + red[5] + red[6] + red[7];
  float mean = s * (1.f / D_);
  float var = sq * (1.f / D_) - mean * mean;
  float rstd = rsqrtf(var + 1e-5f);
  const float4 gv = *(const float4*)(g + tid * 4);
  const float4 bv = *(const float4*)(be + tid * 4);
  float y0 = (v0 - mean) * rstd * gv.x + bv.x;
  float y1 = (v1 - mean) * rstd * gv.y + bv.y;
  float y2 = (v2 - mean) * rstd * gv.z + bv.z;
  float y3 = (v3 - mean) * rstd * gv.w + bv.w;
  float4 o = {y0, y1, y2, y3};
  *(float4*)(outf + off0) = o;
  if (outb) {
    ushort4 ob = {f2bf(y0), f2bf(y1), f2bf(y2), f2bf(y3)};
    *(ushort4*)(outb + off0) = ob;
  }
}

extern "C" void kernel_launch(void* const* d_in, const int* in_sizes, int n_in,
                              void* d_out, int out_size, void* d_ws, size_t ws_size,
                              hipStream_t stream) {
  const float* x = (const float*)d_in[0];
  const int* mask = (const int*)d_in[1];
  const float* Wq = (const float*)d_in[2];
  const float* bq = (const float*)d_in[3];
  const float* Wk = (const float*)d_in[4];
  const float* bk = (const float*)d_in[5];
  const float* Wv = (const float*)d_in[6];
  const float* bv = (const float*)d_in[7];
  const float* Wo = (const float*)d_in[8];
  const float* bo = (const float*)d_in[9];
  const float* W1 = (const float*)d_in[10];
  const float* b1 = (const float*)d_in[11];
  const float* W2 = (const float*)d_in[12];
  const float* b2 = (const float*)d_in[13];
  const float* g1 = (const float*)d_in[14];
  const float* be1 = (const float*)d_in[15];
  const float* g2 = (const float*)d_in[16];
  const float* be2 = (const float*)d_in[17];

  const size_t MB = 1ull << 20;
  char* ws = (char*)d_ws;
  u16* wTq = (u16*)(ws + 0 * MB);   // [wTq;wTk;wTv] contiguous = fused QKV BT
  u16* wTk = (u16*)(ws + 2 * MB);
  u16* wTv = (u16*)(ws + 4 * MB);
  u16* wTo = (u16*)(ws + 6 * MB);
  u16* w1T = (u16*)(ws + 8 * MB);   // FF x D
  u16* w2T = (u16*)(ws + 16 * MB);  // D x FF (live through ffn2)
  u16* xb  = (u16*)(ws + 24 * MB);
  u16* qb  = (u16*)(ws + 32 * MB);
  u16* kb  = (u16*)(ws + 40 * MB);
  u16* vb  = (u16*)(ws + 48 * MB);
  u16* ao  = (u16*)(ws + 56 * MB);
  float* p0 = (float*)(ws + 64 * MB);    // proj partials (sk2): 64..96
  float* p1 = (float*)(ws + 80 * MB);
  float* x1f = (float*)(ws + 24 * MB);   // reuse xb+qb (dead after attn)
  u16*   x1b = (u16*)(ws + 40 * MB);     // reuse kb (dead after attn)
  u16*   h1  = (u16*)(ws + 48 * MB);     // 48..80 (vb/ao/p0 dead after LN1)
  float* f0 = (float*)(ws + 80 * MB);    // ffn2 partials (sk4)
  float* f1 = (float*)(ws + 96 * MB);
  float* f2 = (float*)(ws + 112 * MB);
  float* f3 = (float*)(ws + 0 * MB);     // weights 0..16 dead by ffn2 time

  // fused prep (x cvt + all 6 weight transposes) — 1 launch
  prep_kernel<<<dim3(16384), dim3(256), 0, stream>>>(
      x, xb, W1, w1T, W2, w2T, Wq, Wk, Wv, Wo, wTq, wTk, wTv, wTo);

  gemm_qkv<<<dim3(32, 24), dim3(256), 0, stream>>>(xb, wTq, bq, bk, bv, qb, kb, vb);

  attn_kernel<<<dim3(S_ / 128, B_ * H_), dim3(256), 0, stream>>>(qb, kb, vb, mask, ao);

  // proj: split-K x2 (512 blocks), partials p0,p1
  gemm_bt_sk4<<<dim3(32, 8, 2), dim3(256), 0, stream>>>(
      ao, wTo, bo, p0, p1, p0, p0, 4096, 1024, 1024, 512);

  ln_kernel<<<dim3(4096), dim3(256), 0, stream>>>(x, p0, p1, g1, be1, x1f, x1b);

  gemm_bt_relu<<<dim3(32, 32), dim3(256), 0, stream>>>(x1b, w1T, b1, h1, 4096, 4096, 1024);

  // ffn2: split-K x4 (1024 blocks, 4/CU with launch_bounds), partials f0..f3
  gemm_bt_sk4<<<dim3(32, 8, 4), dim3(256), 0, stream>>>(
      h1, w2T, b2, f0, f1, f2, f3, 4096, 1024, 4096, 1024);

  ln4_kernel<<<dim3(4096), dim3(256), 0, stream>>>(
      x1f, f0, f1, f2, f3, g2, be2, (float*)d_out, (u16*)nullptr);
}

// Round 8
// 369.622 us; speedup vs baseline: 1.1494x; 1.0024x over previous
//
#include <hip/hip_runtime.h>
#include <stdint.h>
#include <stddef.h>

#define B_ 2
#define S_ 2048
#define D_ 1024
#define H_ 16
#define HD_ 64
#define FF_ 4096

typedef unsigned short u16;
typedef __attribute__((ext_vector_type(8))) short bf16x8;
typedef __attribute__((ext_vector_type(4))) float f32x4;

__device__ __forceinline__ u16 f2bf(float f) {
  unsigned u = __float_as_uint(f);
  u += 0x7fffu + ((u >> 16) & 1u);
  return (u16)(u >> 16);
}

__device__ __forceinline__ f32x4 mfma16(bf16x8 a, bf16x8 b, f32x4 c) {
  return __builtin_amdgcn_mfma_f32_16x16x32_bf16(a, b, c, 0, 0, 0);
}

__device__ __forceinline__ void gload16(const void* g, void* l) {
  __builtin_amdgcn_global_load_lds(
      (const __attribute__((address_space(1))) void*)g,
      (__attribute__((address_space(3))) void*)l, 16, 0, 0);
}

// XCD-aware block swizzle (bijective when gridDim.x % 8 == 0).
__device__ __forceinline__ void swizzle_mn(int& mt, int& nt) {
  int gm = gridDim.x;
  if ((gm & 7) == 0) {
    int bid = blockIdx.y * gm + blockIdx.x;
    int mper = gm >> 3;
    int xcd = bid & 7, idx = bid >> 3;
    mt = xcd * mper + (idx % mper);
    nt = idx / mper;
  } else {
    mt = blockIdx.x;
    nt = blockIdx.y;
  }
}

// ---------------- fused prep: x cvt + all weight transposes ----------------
__global__ __launch_bounds__(256) void prep_kernel(
    const float* __restrict__ x, u16* __restrict__ xb,
    const float* __restrict__ W1, u16* __restrict__ w1T,
    const float* __restrict__ W2, u16* __restrict__ w2T,
    const float* __restrict__ Wq, const float* __restrict__ Wk,
    const float* __restrict__ Wv, const float* __restrict__ Wo,
    u16* __restrict__ wTq, u16* __restrict__ wTk,
    u16* __restrict__ wTv, u16* __restrict__ wTo) {
  int bid = blockIdx.x;
  int tid = threadIdx.x;
  if (bid >= 8192 && bid < 12288) {  // cvt path (no barrier)
    int i = (bid - 8192) * 1024 + tid * 4;
    float4 v = *(const float4*)(x + i);
    ushort4 o = { f2bf(v.x), f2bf(v.y), f2bf(v.z), f2bf(v.w) };
    *(ushort4*)(xb + i) = o;
    return;
  }
  const float* W;
  u16* WT;
  int K, N, k0, n0;
  if (bid < 4096) {  // W1
    W = W1; WT = w1T; K = 1024; N = 4096;
    k0 = (bid & 31) * 32; n0 = (bid >> 5) * 32;
  } else if (bid < 8192) {  // W2
    int b2 = bid - 4096;
    W = W2; WT = w2T; K = 4096; N = 1024;
    k0 = (b2 >> 5) * 32; n0 = (b2 & 31) * 32;
  } else {  // 4 x DxD
    int t = bid - 12288;
    int z = t >> 10, r = t & 1023;
    W = z == 0 ? Wq : (z == 1 ? Wk : (z == 2 ? Wv : Wo));
    WT = z == 0 ? wTq : (z == 1 ? wTk : (z == 2 ? wTv : wTo));
    K = 1024; N = 1024;
    k0 = (r & 31) * 32; n0 = (r >> 5) * 32;
  }
  __shared__ u16 t[32][33];
  int r = tid >> 3;
  int c = (tid & 7) << 2;
  float4 v = *(const float4*)(W + (size_t)(k0 + r) * N + n0 + c);
  t[r][c + 0] = f2bf(v.x); t[r][c + 1] = f2bf(v.y);
  t[r][c + 2] = f2bf(v.z); t[r][c + 3] = f2bf(v.w);
  __syncthreads();
  ushort4 o;
  o.x = t[c + 0][r]; o.y = t[c + 1][r]; o.z = t[c + 2][r]; o.w = t[c + 3][r];
  *(ushort4*)(WT + (size_t)(n0 + r) * K + k0 + c) = o;
}

// ======== 128^2 2-phase GEMM macros (qkv + proj keep this template) ========
#define GEMM_STAGE(BUF, KK)                      \
  do {                                           \
    gload16(ga0 + (KK), &As[BUF][c0 * 8]);       \
    gload16(ga1 + (KK), &As[BUF][c1 * 8]);       \
    gload16(gb0 + (KK), &Bs[BUF][c0 * 8]);       \
    gload16(gb1 + (KK), &Bs[BUF][c1 * 8]);       \
  } while (0)

#define GEMM_COMPUTE(BUF)                                                   \
  do {                                                                      \
    bf16x8 af[4], bfr[4];                                                   \
    _Pragma("unroll") for (int i = 0; i < 4; i++)                           \
        af[i] = *(const bf16x8*)&As[BUF][(wm + i * 16 + l16) * 32 + quad * 8]; \
    _Pragma("unroll") for (int j = 0; j < 4; j++)                           \
        bfr[j] = *(const bf16x8*)&Bs[BUF][(wn + j * 16 + l16) * 32 + quad * 8]; \
    _Pragma("unroll") for (int i = 0; i < 4; i++)                           \
        _Pragma("unroll") for (int j = 0; j < 4; j++)                       \
            acc[i][j] = mfma16(af[i], bfr[j], acc[i][j]);                   \
  } while (0)

// ======== 256^2 counted-vmcnt template (ffn1 + ffn2) =======================
// 8 waves (512 thr), BK=32, dbuf LDS 64KB, raw s_barrier + vmcnt(4) (never
// drains in-loop; final step stages a dummy into the dead buffer to keep the
// count uniform). Loads for step j issued during step j-1 -> retire under
// ~32 MFMAs. Linear LDS (no swizzle; m198 showed the counted-vmcnt gain
// survives linear LDS).
#define G2_STAGE(BUF, KK)                        \
  do {                                           \
    gload16(gA0 + (KK), &As[BUF][c0 * 8]);       \
    gload16(gA1 + (KK), &As[BUF][c1 * 8]);       \
    gload16(gB0 + (KK), &Bs[BUF][c0 * 8]);       \
    gload16(gB1 + (KK), &Bs[BUF][c1 * 8]);       \
  } while (0)

#define G2_COMPUTE(BUF)                                                        \
  do {                                                                         \
    bf16x8 bfr[4];                                                             \
    _Pragma("unroll") for (int j = 0; j < 4; j++)                              \
        bfr[j] = *(const bf16x8*)&Bs[BUF][(wn + j * 16 + l16) * 32 + quad * 8]; \
    _Pragma("unroll") for (int i = 0; i < 8; i++) {                            \
      bf16x8 af = *(const bf16x8*)&As[BUF][(wm + i * 16 + l16) * 32 + quad * 8]; \
      _Pragma("unroll") for (int j = 0; j < 4; j++)                            \
          acc[i][j] = mfma16(af, bfr[j], acc[i][j]);                           \
    }                                                                          \
  } while (0)

#define G2_STEP(BUF, NXT, KNEXT)                        \
  do {                                                  \
    G2_STAGE(NXT, KNEXT);                               \
    asm volatile("s_waitcnt vmcnt(4)" ::: "memory");    \
    __builtin_amdgcn_s_barrier();                       \
    asm volatile("" ::: "memory");                      \
    G2_COMPUTE(BUF);                                    \
    asm volatile("" ::: "memory");                      \
    __builtin_amdgcn_s_barrier();                       \
  } while (0)

// ---------------- GEMM 256x256 counted-vmcnt, out bf16+relu [ffn1] ---------
__global__ __launch_bounds__(512, 2) void gemm256_relu(
    const u16* __restrict__ A, const u16* __restrict__ BT,
    const float* __restrict__ bias, u16* __restrict__ outp,
    int M, int N, int K) {
  __shared__ __align__(16) u16 As[2][256 * 32];
  __shared__ __align__(16) u16 Bs[2][256 * 32];
  int tid = threadIdx.x;
  int lane = tid & 63;
  int wave = tid >> 6;            // 0..7
  int quad = lane >> 4;
  int l16 = lane & 15;
  int mt, nt;
  swizzle_mn(mt, nt);
  int m0 = mt * 256;
  int n0 = nt * 256;
  int wm = (wave >> 2) * 128;     // 2 M-groups
  int wn = (wave & 3) * 64;       // 4 N-groups

  f32x4 zero = {0.f, 0.f, 0.f, 0.f};
  f32x4 acc[8][4];
#pragma unroll
  for (int i = 0; i < 8; i++)
#pragma unroll
    for (int j = 0; j < 4; j++) acc[i][j] = zero;

  int c0 = tid, c1 = tid + 512;   // chunk: row = c>>2, kcol = (c&3)*8
  const u16* gA0 = A + (size_t)(m0 + (c0 >> 2)) * K + (c0 & 3) * 8;
  const u16* gA1 = A + (size_t)(m0 + (c1 >> 2)) * K + (c1 & 3) * 8;
  const u16* gB0 = BT + (size_t)(n0 + (c0 >> 2)) * K + (c0 & 3) * 8;
  const u16* gB1 = BT + (size_t)(n0 + (c1 >> 2)) * K + (c1 & 3) * 8;

  G2_STAGE(0, 0);
  for (int k0 = 0; k0 < K; k0 += 64) {
    G2_STEP(0, 1, (k0 + 32 < K) ? k0 + 32 : 0);
    G2_STEP(1, 0, (k0 + 64 < K) ? k0 + 64 : 0);
  }

#pragma unroll
  for (int j = 0; j < 4; j++) {
    int gcol = n0 + wn + j * 16 + l16;
    float bv = bias[gcol];
#pragma unroll
    for (int i = 0; i < 8; i++) {
#pragma unroll
      for (int r = 0; r < 4; r++) {
        int grow = m0 + wm + i * 16 + quad * 4 + r;
        float val = acc[i][j][r] + bv;
        outp[(size_t)grow * N + gcol] = f2bf(val > 0.f ? val : 0.f);
      }
    }
  }
}

// ---------------- GEMM 256x256 counted-vmcnt split-K x4 [ffn2] -------------
__global__ __launch_bounds__(512, 2) void gemm256_sk4(
    const u16* __restrict__ A, const u16* __restrict__ BT,
    const float* __restrict__ bias,
    float* __restrict__ o0, float* __restrict__ o1,
    float* __restrict__ o2, float* __restrict__ o3,
    int M, int N, int K, int Kc) {
  __shared__ __align__(16) u16 As[2][256 * 32];
  __shared__ __align__(16) u16 Bs[2][256 * 32];
  int tid = threadIdx.x;
  int lane = tid & 63;
  int wave = tid >> 6;
  int quad = lane >> 4;
  int l16 = lane & 15;
  int mt, nt;
  swizzle_mn(mt, nt);
  int m0 = mt * 256;
  int n0 = nt * 256;
  int z = blockIdx.z;
  int kb = z * Kc;
  int wm = (wave >> 2) * 128;
  int wn = (wave & 3) * 64;

  f32x4 zero = {0.f, 0.f, 0.f, 0.f};
  f32x4 acc[8][4];
#pragma unroll
  for (int i = 0; i < 8; i++)
#pragma unroll
    for (int j = 0; j < 4; j++) acc[i][j] = zero;

  int c0 = tid, c1 = tid + 512;
  const u16* gA0 = A + (size_t)(m0 + (c0 >> 2)) * K + (c0 & 3) * 8 + kb;
  const u16* gA1 = A + (size_t)(m0 + (c1 >> 2)) * K + (c1 & 3) * 8 + kb;
  const u16* gB0 = BT + (size_t)(n0 + (c0 >> 2)) * K + (c0 & 3) * 8 + kb;
  const u16* gB1 = BT + (size_t)(n0 + (c1 >> 2)) * K + (c1 & 3) * 8 + kb;

  G2_STAGE(0, 0);
  for (int k0 = 0; k0 < Kc; k0 += 64) {
    G2_STEP(0, 1, (k0 + 32 < Kc) ? k0 + 32 : 0);
    G2_STEP(1, 0, (k0 + 64 < Kc) ? k0 + 64 : 0);
  }

  float* outz = z == 0 ? o0 : (z == 1 ? o1 : (z == 2 ? o2 : o3));
  float biasmul = (z == 0) ? 1.f : 0.f;
#pragma unroll
  for (int j = 0; j < 4; j++) {
    int gcol = n0 + wn + j * 16 + l16;
    float bv = bias[gcol] * biasmul;
#pragma unroll
    for (int i = 0; i < 8; i++) {
#pragma unroll
      for (int r = 0; r < 4; r++) {
        int grow = m0 + wm + i * 16 + quad * 4 + r;
        outz[(size_t)grow * N + gcol] = acc[i][j][r] + bv;
      }
    }
  }
}

// ---------------- GEMM 128x128 BK=32 2-phase split-K (proj) ----------------
__global__ __launch_bounds__(256, 4) void gemm_bt_sk4(
    const u16* __restrict__ A, const u16* __restrict__ BT,
    const float* __restrict__ bias,
    float* __restrict__ o0, float* __restrict__ o1,
    float* __restrict__ o2, float* __restrict__ o3,
    int M, int N, int K, int Kc) {
  __shared__ __align__(16) u16 As[2][128 * 32];
  __shared__ __align__(16) u16 Bs[2][128 * 32];
  int tid = threadIdx.x;
  int lane = tid & 63;
  int wave = tid >> 6;
  int quad = lane >> 4;
  int l16 = lane & 15;
  int mt, nt;
  swizzle_mn(mt, nt);
  int m0 = mt * 128;
  int n0 = nt * 128;
  int z = blockIdx.z;
  int kb = z * Kc;
  int wm = (wave >> 1) * 64;
  int wn = (wave & 1) * 64;

  f32x4 zero = {0.f, 0.f, 0.f, 0.f};
  f32x4 acc[4][4];
#pragma unroll
  for (int i = 0; i < 4; i++)
#pragma unroll
    for (int j = 0; j < 4; j++) acc[i][j] = zero;

  int c0 = tid, c1 = tid + 256;
  const u16* ga0 = A + (size_t)(m0 + (c0 >> 2)) * K + (c0 & 3) * 8 + kb;
  const u16* ga1 = A + (size_t)(m0 + (c1 >> 2)) * K + (c1 & 3) * 8 + kb;
  const u16* gb0 = BT + (size_t)(n0 + (c0 >> 2)) * K + (c0 & 3) * 8 + kb;
  const u16* gb1 = BT + (size_t)(n0 + (c1 >> 2)) * K + (c1 & 3) * 8 + kb;

  GEMM_STAGE(0, 0);
  __syncthreads();
  for (int k0 = 0; k0 < Kc; k0 += 64) {
    if (k0 + 32 < Kc) GEMM_STAGE(1, k0 + 32);
    GEMM_COMPUTE(0);
    __syncthreads();
    if (k0 + 64 < Kc) GEMM_STAGE(0, k0 + 64);
    GEMM_COMPUTE(1);
    __syncthreads();
  }

  float* outz = z == 0 ? o0 : (z == 1 ? o1 : (z == 2 ? o2 : o3));
  float biasmul = (z == 0) ? 1.f : 0.f;
#pragma unroll
  for (int j = 0; j < 4; j++) {
    int gcol = n0 + wn + j * 16 + l16;
    float bv = bias[gcol] * biasmul;
#pragma unroll
    for (int i = 0; i < 4; i++) {
#pragma unroll
      for (int r = 0; r < 4; r++) {
        int grow = m0 + wm + i * 16 + quad * 4 + r;
        outz[(size_t)grow * N + gcol] = acc[i][j][r] + bv;
      }
    }
  }
}

// ---------------- fused QKV GEMM BK=32 2-phase -----------------------------
__global__ __launch_bounds__(256, 4) void gemm_qkv(
    const u16* __restrict__ A, const u16* __restrict__ BT,
    const float* __restrict__ bq, const float* __restrict__ bk,
    const float* __restrict__ bvp,
    u16* __restrict__ qb, u16* __restrict__ kb, u16* __restrict__ vb) {
  const int K = 1024;
  __shared__ __align__(16) u16 As[2][128 * 32];
  __shared__ __align__(16) u16 Bs[2][128 * 32];
  int tid = threadIdx.x;
  int lane = tid & 63;
  int wave = tid >> 6;
  int quad = lane >> 4;
  int l16 = lane & 15;
  int mt, nt;
  swizzle_mn(mt, nt);
  int m0 = mt * 128;
  int n0 = nt * 128;
  int wm = (wave >> 1) * 64;
  int wn = (wave & 1) * 64;

  f32x4 zero = {0.f, 0.f, 0.f, 0.f};
  f32x4 acc[4][4];
#pragma unroll
  for (int i = 0; i < 4; i++)
#pragma unroll
    for (int j = 0; j < 4; j++) acc[i][j] = zero;

  int c0 = tid, c1 = tid + 256;
  const u16* ga0 = A + (size_t)(m0 + (c0 >> 2)) * K + (c0 & 3) * 8;
  const u16* ga1 = A + (size_t)(m0 + (c1 >> 2)) * K + (c1 & 3) * 8;
  const u16* gb0 = BT + (size_t)(n0 + (c0 >> 2)) * K + (c0 & 3) * 8;
  const u16* gb1 = BT + (size_t)(n0 + (c1 >> 2)) * K + (c1 & 3) * 8;

  GEMM_STAGE(0, 0);
  __syncthreads();
  for (int k0 = 0; k0 < K; k0 += 64) {
    if (k0 + 32 < K) GEMM_STAGE(1, k0 + 32);
    GEMM_COMPUTE(0);
    __syncthreads();
    if (k0 + 64 < K) GEMM_STAGE(0, k0 + 64);
    GEMM_COMPUTE(1);
    __syncthreads();
  }

  int region = n0 >> 10;
  const float* bias = region == 0 ? bq : (region == 1 ? bk : bvp);
  u16* outp = region == 0 ? qb : (region == 1 ? kb : vb);
  float scale = region == 0 ? 0.125f * 1.4426950408889634f : 1.f;

#pragma unroll
  for (int j = 0; j < 4; j++) {
    int gcol = (n0 & 1023) + wn + j * 16 + l16;
    float bv = bias[gcol];
    int h = gcol >> 6, hd = gcol & 63;
#pragma unroll
    for (int i = 0; i < 4; i++) {
#pragma unroll
      for (int r = 0; r < 4; r++) {
        int grow = m0 + wm + i * 16 + quad * 4 + r;
        float val = (acc[i][j][r] + bv) * scale;
        int b = grow >> 11, s = grow & 2047;
        if (region < 2) {
          outp[(((size_t)(b * H_ + h)) * S_ + s) * HD_ + hd] = f2bf(val);
        } else {
          outp[(((size_t)(b * H_ + h)) * HD_ + hd) * S_ + s] = f2bf(val);
        }
      }
    }
  }
}

// ---------------- flash attention: MQ=32/wave, double-buffered K/V ---------
// (exact R1 kernel — known 73 us)
__global__ __launch_bounds__(256, 2) void attn_kernel(
    const u16* __restrict__ q, const u16* __restrict__ k,
    const u16* __restrict__ vt, const int* __restrict__ mask,
    u16* __restrict__ ao) {
  __shared__ __align__(16) u16 Ks[2][64 * 72];
  __shared__ __align__(16) u16 Vs[2][64 * 72];
  __shared__ __align__(16) u16 Ps[4][32 * 72];
  int tid = threadIdx.x;
  int lane = tid & 63;
  int wave = tid >> 6;
  int quad = lane >> 4;
  int l16 = lane & 15;
  int bh = blockIdx.y;
  int b = bh >> 4;
  int h = bh & 15;
  int qrow0 = blockIdx.x * 128 + wave * 32;

  const u16* qh = q + (size_t)bh * S_ * HD_;
  const u16* kh = k + (size_t)bh * S_ * HD_;
  const u16* vh = vt + (size_t)bh * HD_ * S_;

  bf16x8 qfA0 = *(const bf16x8*)(qh + (size_t)(qrow0 + l16) * HD_ + quad * 8);
  bf16x8 qfA1 = *(const bf16x8*)(qh + (size_t)(qrow0 + l16) * HD_ + 32 + quad * 8);
  bf16x8 qfB0 = *(const bf16x8*)(qh + (size_t)(qrow0 + 16 + l16) * HD_ + quad * 8);
  bf16x8 qfB1 = *(const bf16x8*)(qh + (size_t)(qrow0 + 16 + l16) * HD_ + 32 + quad * 8);

  int sr = tid >> 3, sc = tid & 7;
  const u16* kg0 = kh + sr * HD_ + sc * 8;
  const u16* kg1 = kh + (sr + 32) * HD_ + sc * 8;
  const u16* vg0 = vh + (size_t)sr * S_ + sc * 8;
  const u16* vg1 = vh + (size_t)(sr + 32) * S_ + sc * 8;
  int kr0 = (sr & 1) * 16 + (sr >> 1);
  int ko0 = kr0 * 72 + sc * 8;
  int ko1 = (32 + kr0) * 72 + sc * 8;
  int vo0 = sr * 72 + sc * 8;
  int vo1 = (sr + 32) * 72 + sc * 8;
  const int* mrow = mask + b * S_ + 2 * l16;

  float l_pA[4] = {0.f, 0.f, 0.f, 0.f};
  float l_pB[4] = {0.f, 0.f, 0.f, 0.f};
  f32x4 zero = {0.f, 0.f, 0.f, 0.f};
  f32x4 o_accA[4], o_accB[4];
#pragma unroll
  for (int c = 0; c < 4; c++) { o_accA[c] = zero; o_accB[c] = zero; }

  u16* pw = &Ps[wave][0];

  bf16x8 kv0 = *(const bf16x8*)(kg0);
  bf16x8 kv1 = *(const bf16x8*)(kg1);
  bf16x8 vv0 = *(const bf16x8*)(vg0);
  bf16x8 vv1 = *(const bf16x8*)(vg1);
  *(bf16x8*)&Ks[0][ko0] = kv0;
  *(bf16x8*)&Ks[0][ko1] = kv1;
  *(bf16x8*)&Vs[0][vo0] = vv0;
  *(bf16x8*)&Vs[0][vo1] = vv1;
  kv0 = *(const bf16x8*)(kg0 + (size_t)64 * HD_);
  kv1 = *(const bf16x8*)(kg1 + (size_t)64 * HD_);
  vv0 = *(const bf16x8*)(vg0 + 64);
  vv1 = *(const bf16x8*)(vg1 + 64);

  int cur = 0;
  for (int kt = 0; kt < S_; kt += 64) {
    int2 mk0 = *(const int2*)(mrow + kt);
    int2 mk1 = *(const int2*)(mrow + kt + 32);

    __syncthreads();
    if (kt + 64 < S_) {
      int alt = cur ^ 1;
      *(bf16x8*)&Ks[alt][ko0] = kv0;
      *(bf16x8*)&Ks[alt][ko1] = kv1;
      *(bf16x8*)&Vs[alt][vo0] = vv0;
      *(bf16x8*)&Vs[alt][vo1] = vv1;
      int nk = (kt + 128) & (S_ - 1);
      kv0 = *(const bf16x8*)(kg0 + (size_t)nk * HD_);
      kv1 = *(const bf16x8*)(kg1 + (size_t)nk * HD_);
      vv0 = *(const bf16x8*)(vg0 + nk);
      vv1 = *(const bf16x8*)(vg1 + nk);
    }

    const u16* ksb = &Ks[cur][0];
    const u16* vsb = &Vs[cur][0];
#pragma unroll
    for (int g = 0; g < 2; g++) {
      int2 mk = g == 0 ? mk0 : mk1;
      int rowe = (g * 32 + l16) * 72;
      int rowo = (g * 32 + 16 + l16) * 72;
      bf16x8 e0 = *(const bf16x8*)&ksb[rowe + quad * 8];
      bf16x8 e1 = *(const bf16x8*)&ksb[rowe + 32 + quad * 8];
      bf16x8 o0 = *(const bf16x8*)&ksb[rowo + quad * 8];
      bf16x8 o1 = *(const bf16x8*)&ksb[rowo + 32 + quad * 8];
      f32x4 seA = mfma16(qfA1, e1, mfma16(qfA0, e0, zero));
      f32x4 soA = mfma16(qfA1, o1, mfma16(qfA0, o0, zero));
      f32x4 seB = mfma16(qfB1, e1, mfma16(qfB0, e0, zero));
      f32x4 soB = mfma16(qfB1, o1, mfma16(qfB0, o0, zero));
#pragma unroll
      for (int r = 0; r < 4; r++) {
        float pA0 = mk.x ? exp2f(seA[r]) : 0.f;
        float pA1 = mk.y ? exp2f(soA[r]) : 0.f;
        float pB0 = mk.x ? exp2f(seB[r]) : 0.f;
        float pB1 = mk.y ? exp2f(soB[r]) : 0.f;
        l_pA[r] += pA0 + pA1;
        l_pB[r] += pB0 + pB1;
        unsigned pkA = __builtin_amdgcn_perm(__float_as_uint(pA1),
                                             __float_as_uint(pA0), 0x07060302u);
        unsigned pkB = __builtin_amdgcn_perm(__float_as_uint(pB1),
                                             __float_as_uint(pB0), 0x07060302u);
        *(unsigned*)&pw[(quad * 4 + r) * 72 + g * 32 + 2 * l16] = pkA;
        *(unsigned*)&pw[(16 + quad * 4 + r) * 72 + g * 32 + 2 * l16] = pkB;
      }
    }
    bf16x8 pfA0 = *(const bf16x8*)&pw[l16 * 72 + quad * 8];
    bf16x8 pfA1 = *(const bf16x8*)&pw[l16 * 72 + 32 + quad * 8];
    bf16x8 pfB0 = *(const bf16x8*)&pw[(16 + l16) * 72 + quad * 8];
    bf16x8 pfB1 = *(const bf16x8*)&pw[(16 + l16) * 72 + 32 + quad * 8];
#pragma unroll
    for (int c = 0; c < 4; c++) {
      bf16x8 vf0 = *(const bf16x8*)&vsb[(c * 16 + l16) * 72 + quad * 8];
      bf16x8 vf1 = *(const bf16x8*)&vsb[(c * 16 + l16) * 72 + 32 + quad * 8];
      o_accA[c] = mfma16(pfA1, vf1, mfma16(pfA0, vf0, o_accA[c]));
      o_accB[c] = mfma16(pfB1, vf1, mfma16(pfB0, vf0, o_accB[c]));
    }
    cur ^= 1;
  }

#pragma unroll
  for (int r = 0; r < 4; r++) {
    float sA = l_pA[r], sB = l_pB[r];
#pragma unroll
    for (int off = 1; off < 16; off <<= 1) {
      sA += __shfl_xor(sA, off);
      sB += __shfl_xor(sB, off);
    }
    float invA = 1.f / sA, invB = 1.f / sB;
    int srowA = qrow0 + quad * 4 + r;
    int srowB = qrow0 + 16 + quad * 4 + r;
#pragma unroll
    for (int c = 0; c < 4; c++) {
      ao[((size_t)(b * S_ + srowA)) * D_ + h * HD_ + c * 16 + l16] =
          f2bf(o_accA[c][r] * invA);
      ao[((size_t)(b * S_ + srowB)) * D_ + h * HD_ + c * 16 + l16] =
          f2bf(o_accB[c][r] * invB);
    }
  }
}

// ---------------- residual (2 partials) + layernorm ----------------
__global__ __launch_bounds__(256) void ln_kernel(
    const float* __restrict__ xa, const float* __restrict__ add0,
    const float* __restrict__ add1,
    const float* __restrict__ g, const float* __restrict__ be,
    float* __restrict__ outf, u16* __restrict__ outb) {
  int row = blockIdx.x;
  int tid = threadIdx.x;
  int lane = tid & 63;
  int wv = tid >> 6;
  const float4 a = *(const float4*)(xa + (size_t)row * D_ + tid * 4);
  const float4 c = *(const float4*)(add0 + (size_t)row * D_ + tid * 4);
  const float4 d = *(const float4*)(add1 + (size_t)row * D_ + tid * 4);
  float v0 = a.x + c.x + d.x, v1 = a.y + c.y + d.y;
  float v2 = a.z + c.z + d.z, v3 = a.w + c.w + d.w;
  float s = v0 + v1 + v2 + v3;
  float sq = v0 * v0 + v1 * v1 + v2 * v2 + v3 * v3;
#pragma unroll
  for (int off = 1; off < 64; off <<= 1) {
    s += __shfl_xor(s, off);
    sq += __shfl_xor(sq, off);
  }
  __shared__ float red[8];
  if (lane == 0) { red[wv] = s; red[4 + wv] = sq; }
  __syncthreads();
  s = red[0] + red[1] + red[2] + red[3];
  sq = red[4] + red[5] + red[6] + red[7];
  float mean = s * (1.f / D_);
  float var = sq * (1.f / D_) - mean * mean;
  float rstd = rsqrtf(var + 1e-5f);
  const float4 gv = *(const float4*)(g + tid * 4);
  const float4 bv = *(const float4*)(be + tid * 4);
  float y0 = (v0 - mean) * rstd * gv.x + bv.x;
  float y1 = (v1 - mean) * rstd * gv.y + bv.y;
  float y2 = (v2 - mean) * rstd * gv.z + bv.z;
  float y3 = (v3 - mean) * rstd * gv.w + bv.w;
  float4 o = {y0, y1, y2, y3};
  *(float4*)(outf + (size_t)row * D_ + tid * 4) = o;
  if (outb) {
    ushort4 ob = {f2bf(y0), f2bf(y1), f2bf(y2), f2bf(y3)};
    *(ushort4*)(outb + (size_t)row * D_ + tid * 4) = ob;
  }
}

// ---------------- residual (4 partials) + layernorm ----------------
__global__ __launch_bounds__(256) void ln4_kernel(
    const float* __restrict__ xa,
    const float* __restrict__ a0, const float* __restrict__ a1,
    const float* __restrict__ a2, const float* __restrict__ a3,
    const float* __restrict__ g, const float* __restrict__ be,
    float* __restrict__ outf, u16* __restrict__ outb) {
  int row = blockIdx.x;
  int tid = threadIdx.x;
  int lane = tid & 63;
  int wv = tid >> 6;
  size_t off0 = (size_t)row * D_ + tid * 4;
  const float4 a = *(const float4*)(xa + off0);
  const float4 c0 = *(const float4*)(a0 + off0);
  const float4 c1 = *(const float4*)(a1 + off0);
  const float4 c2 = *(const float4*)(a2 + off0);
  const float4 c3 = *(const float4*)(a3 + off0);
  float v0 = a.x + (c0.x + c1.x) + (c2.x + c3.x);
  float v1 = a.y + (c0.y + c1.y) + (c2.y + c3.y);
  float v2 = a.z + (c0.z + c1.z) + (c2.z + c3.z);
  float v3 = a.w + (c0.w + c1.w) + (c2.w + c3.w);
  float s = v0 + v1 + v2 + v3;
  float sq = v0 * v0 + v1 * v1 + v2 * v2 + v3 * v3;
#pragma unroll
  for (int off = 1; off < 64; off <<= 1) {
    s += __shfl_xor(s, off);
    sq += __shfl_xor(sq, off);
  }
  __shared__ float red[8];
  if (lane == 0) { red[wv] = s; red[4 + wv] = sq; }
  __syncthreads();
  s = red[0] + red[1] + red[2] + red[3];
  sq = red[4] + red[5] + red[6] + red[7];
  float mean = s * (1.f / D_);
  float var = sq * (1.f / D_) - mean * mean;
  float rstd = rsqrtf(var + 1e-5f);
  const float4 gv = *(const float4*)(g + tid * 4);
  const float4 bv = *(const float4*)(be + tid * 4);
  float y0 = (v0 - mean) * rstd * gv.x + bv.x;
  float y1 = (v1 - mean) * rstd * gv.y + bv.y;
  float y2 = (v2 - mean) * rstd * gv.z + bv.z;
  float y3 = (v3 - mean) * rstd * gv.w + bv.w;
  float4 o = {y0, y1, y2, y3};
  *(float4*)(outf + off0) = o;
  if (outb) {
    ushort4 ob = {f2bf(y0), f2bf(y1), f2bf(y2), f2bf(y3)};
    *(ushort4*)(outb + off0) = ob;
  }
}

extern "C" void kernel_launch(void* const* d_in, const int* in_sizes, int n_in,
                              void* d_out, int out_size, void* d_ws, size_t ws_size,
                              hipStream_t stream) {
  const float* x = (const float*)d_in[0];
  const int* mask = (const int*)d_in[1];
  const float* Wq = (const float*)d_in[2];
  const float* bq = (const float*)d_in[3];
  const float* Wk = (const float*)d_in[4];
  const float* bk = (const float*)d_in[5];
  const float* Wv = (const float*)d_in[6];
  const float* bv = (const float*)d_in[7];
  const float* Wo = (const float*)d_in[8];
  const float* bo = (const float*)d_in[9];
  const float* W1 = (const float*)d_in[10];
  const float* b1 = (const float*)d_in[11];
  const float* W2 = (const float*)d_in[12];
  const float* b2 = (const float*)d_in[13];
  const float* g1 = (const float*)d_in[14];
  const float* be1 = (const float*)d_in[15];
  const float* g2 = (const float*)d_in[16];
  const float* be2 = (const float*)d_in[17];

  const size_t MB = 1ull << 20;
  char* ws = (char*)d_ws;
  u16* wTq = (u16*)(ws + 0 * MB);   // [wTq;wTk;wTv] contiguous = fused QKV BT
  u16* wTk = (u16*)(ws + 2 * MB);
  u16* wTv = (u16*)(ws + 4 * MB);
  u16* wTo = (u16*)(ws + 6 * MB);
  u16* w1T = (u16*)(ws + 8 * MB);   // FF x D
  u16* w2T = (u16*)(ws + 16 * MB);  // D x FF (live through ffn2)
  u16* xb  = (u16*)(ws + 24 * MB);
  u16* qb  = (u16*)(ws + 32 * MB);
  u16* kb  = (u16*)(ws + 40 * MB);
  u16* vb  = (u16*)(ws + 48 * MB);
  u16* ao  = (u16*)(ws + 56 * MB);
  float* p0 = (float*)(ws + 64 * MB);    // proj partials (sk2): 64..96
  float* p1 = (float*)(ws + 80 * MB);
  float* x1f = (float*)(ws + 24 * MB);   // reuse xb+qb (dead after attn)
  u16*   x1b = (u16*)(ws + 40 * MB);     // reuse kb (dead after attn)
  u16*   h1  = (u16*)(ws + 48 * MB);     // 48..80 (vb/ao/p0 dead after LN1)
  float* f0 = (float*)(ws + 80 * MB);    // ffn2 partials (sk4)
  float* f1 = (float*)(ws + 96 * MB);
  float* f2 = (float*)(ws + 112 * MB);
  float* f3 = (float*)(ws + 0 * MB);     // weights 0..16 dead by ffn2 time

  // fused prep (x cvt + all 6 weight transposes) — 1 launch
  prep_kernel<<<dim3(16384), dim3(256), 0, stream>>>(
      x, xb, W1, w1T, W2, w2T, Wq, Wk, Wv, Wo, wTq, wTk, wTv, wTo);

  gemm_qkv<<<dim3(32, 24), dim3(256), 0, stream>>>(xb, wTq, bq, bk, bv, qb, kb, vb);

  attn_kernel<<<dim3(S_ / 128, B_ * H_), dim3(256), 0, stream>>>(qb, kb, vb, mask, ao);

  // proj: split-K x2 (512 blocks), partials p0,p1
  gemm_bt_sk4<<<dim3(32, 8, 2), dim3(256), 0, stream>>>(
      ao, wTo, bo, p0, p1, p0, p0, 4096, 1024, 1024, 512);

  ln_kernel<<<dim3(4096), dim3(256), 0, stream>>>(x, p0, p1, g1, be1, x1f, x1b);

  // ffn1: 256^2 counted-vmcnt template, 256 blocks (1/CU)
  gemm256_relu<<<dim3(16, 16), dim3(512), 0, stream>>>(
      x1b, w1T, b1, h1, 4096, 4096, 1024);

  // ffn2: 256^2 counted-vmcnt split-K x4 (64 tiles x 4 = 256 blocks)
  gemm256_sk4<<<dim3(16, 4, 4), dim3(512), 0, stream>>>(
      h1, w2T, b2, f0, f1, f2, f3, 4096, 1024, 4096, 1024);

  ln4_kernel<<<dim3(4096), dim3(256), 0, stream>>>(
      x1f, f0, f1, f2, f3, g2, be2, (float*)d_out, (u16*)nullptr);
}